// Round 1
// baseline (684.687 us; speedup 1.0000x reference)
//
#include <hip/hip_runtime.h>
#include <hip/hip_bf16.h>
#include <math.h>

#define B_ 2
#define N_ 1024
#define H_ 512
#define NH_ 8
#define HD_ 64
#define G_ 50
constexpr float MAXD = 10.0f;

// ---------------- LayerNorm (one block per row of 512) ----------------
__global__ __launch_bounds__(128) void ln_k(const float* __restrict__ x,
                                            const float* __restrict__ g,
                                            const float* __restrict__ b,
                                            float* __restrict__ out) {
  int row = blockIdx.x;
  const float* xr = x + (size_t)row * H_;
  int t = threadIdx.x;
  float4 v = *(const float4*)(xr + t * 4);
  float s = v.x + v.y + v.z + v.w;
  float sq = v.x * v.x + v.y * v.y + v.z * v.z + v.w * v.w;
  #pragma unroll
  for (int m = 1; m < 64; m <<= 1) {
    s += __shfl_xor(s, m, 64);
    sq += __shfl_xor(sq, m, 64);
  }
  __shared__ float red[2][2];
  int wid = t >> 6;
  if ((t & 63) == 0) { red[wid][0] = s; red[wid][1] = sq; }
  __syncthreads();
  s = red[0][0] + red[1][0];
  sq = red[0][1] + red[1][1];
  float mu = s * (1.0f / H_);
  float var = sq * (1.0f / H_) - mu * mu;
  float rs = rsqrtf(var + 1e-5f);
  float4 gg = *(const float4*)(g + t * 4);
  float4 bb = *(const float4*)(b + t * 4);
  float4 o;
  o.x = (v.x - mu) * rs * gg.x + bb.x;
  o.y = (v.y - mu) * rs * gg.y + bb.y;
  o.z = (v.z - mu) * rs * gg.z + bb.z;
  o.w = (v.w - mu) * rs * gg.w + bb.w;
  *(float4*)(out + (size_t)row * H_ + t * 4) = o;
}

// ---------------- Tiled fp32 GEMM: C = A(MxK) @ W(KxN) + bias, epilogues ----------------
constexpr int BM = 64, BNt = 64, BK = 16;
enum { EPI_PLAIN = 0, EPI_QKV = 1, EPI_RES = 2, EPI_GELU = 3 };

template <int EPI>
__global__ __launch_bounds__(256) void gemm_k(const float* __restrict__ A,
                                              const float* __restrict__ W,
                                              const float* __restrict__ bias,
                                              const float* __restrict__ resid,
                                              float* __restrict__ out,
                                              int M, int Nc, int K) {
  __shared__ float As[BK][BM + 4];  // stride 68: conflict-free, 16B-aligned float4
  __shared__ float Ws[BK][BNt + 4];
  int t = threadIdx.x;
  int tx = t & 15, ty = t >> 4;
  int row0 = blockIdx.y * BM, col0 = blockIdx.x * BNt;
  float acc[4][4] = {};
  for (int k0 = 0; k0 < K; k0 += BK) {
    {
      int kk = t & 15, rr0 = t >> 4;
      #pragma unroll
      for (int p = 0; p < 4; ++p) {
        int rr = rr0 + p * 16;
        As[kk][rr] = A[(size_t)(row0 + rr) * K + k0 + kk];
      }
      int cc = t & 63, kk0 = t >> 6;
      #pragma unroll
      for (int p = 0; p < 4; ++p) {
        int kk2 = kk0 + p * 4;
        Ws[kk2][cc] = W[(size_t)(k0 + kk2) * Nc + col0 + cc];
      }
    }
    __syncthreads();
    #pragma unroll
    for (int kk = 0; kk < BK; ++kk) {
      float4 a = *(const float4*)&As[kk][ty * 4];
      float4 b4 = *(const float4*)&Ws[kk][tx * 4];
      float av[4] = {a.x, a.y, a.z, a.w};
      float bv[4] = {b4.x, b4.y, b4.z, b4.w};
      #pragma unroll
      for (int i = 0; i < 4; ++i)
        #pragma unroll
        for (int j = 0; j < 4; ++j) acc[i][j] = fmaf(av[i], bv[j], acc[i][j]);
    }
    __syncthreads();
  }
  #pragma unroll
  for (int i = 0; i < 4; ++i) {
    int row = row0 + ty * 4 + i;
    #pragma unroll
    for (int j = 0; j < 4; ++j) {
      int col = col0 + tx * 4 + j;
      float vv = acc[i][j] + bias[col];
      if constexpr (EPI == EPI_QKV) {
        int bb = row >> 10, n = row & (N_ - 1);
        int h = col >> 6, d = col & 63;
        out[(((size_t)(bb * NH_ + h)) * N_ + n) * HD_ + d] = vv;
      } else if constexpr (EPI == EPI_RES) {
        out[(size_t)row * Nc + col] = resid[(size_t)row * Nc + col] + vv;
      } else if constexpr (EPI == EPI_GELU) {
        out[(size_t)row * Nc + col] = 0.5f * vv * (1.0f + erff(vv * 0.70710678118654752f));
      } else {
        out[(size_t)row * Nc + col] = vv;
      }
    }
  }
}

// ---------------- Fused flash attention with RBF distance bias ----------------
constexpr int QT = 32, KT = 64;
__global__ __launch_bounds__(256) void attn_k(
    const float* __restrict__ q, const float* __restrict__ k, const float* __restrict__ v,
    const float* __restrict__ dist, const int* __restrict__ mask,
    const float* __restrict__ widths, const float* __restrict__ dp_w,
    const float* __restrict__ dp_b, float* __restrict__ attn_out) {
  int qt = blockIdx.x, h = blockIdx.y, b = blockIdx.z;
  int i0 = qt * QT;
  __shared__ float qT[HD_][QT + 4];   // [d][qi]
  __shared__ float kT[HD_][KT + 4];   // [d][j]
  __shared__ float vS[KT][HD_ + 4];   // [j][d]
  __shared__ float sbuf[QT][KT + 4];  // [qi][j]
  __shared__ float pT[KT][QT + 4];    // [j][qi]
  __shared__ float mrow[QT], lrow[QT], arow[QT];
  __shared__ float wcol[G_], invd[G_];
  int t = threadIdx.x;
  int tx = t & 15, ty = t >> 4;
  if (t < QT) { mrow[t] = -1e30f; lrow[t] = 0.f; }
  if (t < G_) {
    wcol[t] = dp_w[t * NH_ + h];
    float w = widths[t];
    invd[t] = -1.0f / (2.0f * w * w);
  }
  const size_t headoff = ((size_t)(b * NH_ + h)) * N_ * HD_;
  const float* qbase = q + headoff;
  const float* kbase = k + headoff;
  const float* vbase = v + headoff;
  for (int idx = t; idx < QT * HD_; idx += 256) {
    int d = idx & 63, qi = idx >> 6;
    qT[d][qi] = qbase[(size_t)(i0 + qi) * HD_ + d];
  }
  float bh = dp_b[h];
  float oacc[2][4] = {};
  for (int j0 = 0; j0 < N_; j0 += KT) {
    __syncthreads();  // protect kT/vS/pT from prev-iter readers; covers init first iter
    for (int idx = t; idx < KT * HD_; idx += 256) {
      int d = idx & 63, j = idx >> 6;
      kT[d][j] = kbase[(size_t)(j0 + j) * HD_ + d];
      vS[j][d] = vbase[(size_t)(j0 + j) * HD_ + d];
    }
    __syncthreads();
    // scores: qi = ty*2..+1, j = tx*4..+3
    float sa[2][4] = {};
    #pragma unroll 16
    for (int d = 0; d < HD_; ++d) {
      float2 qa = *(const float2*)&qT[d][ty * 2];
      float4 kb = *(const float4*)&kT[d][tx * 4];
      sa[0][0] = fmaf(qa.x, kb.x, sa[0][0]);
      sa[0][1] = fmaf(qa.x, kb.y, sa[0][1]);
      sa[0][2] = fmaf(qa.x, kb.z, sa[0][2]);
      sa[0][3] = fmaf(qa.x, kb.w, sa[0][3]);
      sa[1][0] = fmaf(qa.y, kb.x, sa[1][0]);
      sa[1][1] = fmaf(qa.y, kb.y, sa[1][1]);
      sa[1][2] = fmaf(qa.y, kb.z, sa[1][2]);
      sa[1][3] = fmaf(qa.y, kb.w, sa[1][3]);
    }
    #pragma unroll
    for (int i = 0; i < 2; ++i) {
      int qi = ty * 2 + i;
      #pragma unroll
      for (int j = 0; j < 4; ++j) {
        int jj = tx * 4 + j;
        float dd = dist[((size_t)b * N_ + (i0 + qi)) * N_ + j0 + jj];
        float bacc = 0.f;
        for (int g = 0; g < G_; ++g) {
          float diff = dd - (float)g * (MAXD / 49.0f);
          bacc = fmaf(__expf(diff * diff * invd[g]), wcol[g], bacc);
        }
        float s = sa[i][j] * 0.125f + bacc + bh;
        if (mask[b * N_ + j0 + jj] == 0) s = -1e9f;
        sbuf[qi][jj] = s;
      }
    }
    __syncthreads();
    {  // online softmax: 8 threads per row, 8 j each
      int rrow = t >> 3, c = t & 7;
      float sv[8];
      float tm = -1e30f;
      #pragma unroll
      for (int jj = 0; jj < 8; ++jj) {
        sv[jj] = sbuf[rrow][c * 8 + jj];
        tm = fmaxf(tm, sv[jj]);
      }
      #pragma unroll
      for (int m2 = 1; m2 < 8; m2 <<= 1) tm = fmaxf(tm, __shfl_xor(tm, m2, 64));
      float mold = mrow[rrow];
      float mnew = fmaxf(mold, tm);
      float alpha = __expf(mold - mnew);
      float psum = 0.f;
      #pragma unroll
      for (int jj = 0; jj < 8; ++jj) {
        float p = __expf(sv[jj] - mnew);
        pT[c * 8 + jj][rrow] = p;
        psum += p;
      }
      #pragma unroll
      for (int m2 = 1; m2 < 8; m2 <<= 1) psum += __shfl_xor(psum, m2, 64);
      if (c == 0) {
        lrow[rrow] = lrow[rrow] * alpha + psum;
        mrow[rrow] = mnew;
        arow[rrow] = alpha;
      }
    }
    __syncthreads();
    // PV accumulate
    float a0 = arow[ty * 2], a1 = arow[ty * 2 + 1];
    #pragma unroll
    for (int j2 = 0; j2 < 4; ++j2) { oacc[0][j2] *= a0; oacc[1][j2] *= a1; }
    #pragma unroll 16
    for (int j = 0; j < KT; ++j) {
      float2 pa = *(const float2*)&pT[j][ty * 2];
      float4 vb4 = *(const float4*)&vS[j][tx * 4];
      oacc[0][0] = fmaf(pa.x, vb4.x, oacc[0][0]);
      oacc[0][1] = fmaf(pa.x, vb4.y, oacc[0][1]);
      oacc[0][2] = fmaf(pa.x, vb4.z, oacc[0][2]);
      oacc[0][3] = fmaf(pa.x, vb4.w, oacc[0][3]);
      oacc[1][0] = fmaf(pa.y, vb4.x, oacc[1][0]);
      oacc[1][1] = fmaf(pa.y, vb4.y, oacc[1][1]);
      oacc[1][2] = fmaf(pa.y, vb4.z, oacc[1][2]);
      oacc[1][3] = fmaf(pa.y, vb4.w, oacc[1][3]);
    }
  }
  float il0 = 1.0f / lrow[ty * 2];
  float il1 = 1.0f / lrow[ty * 2 + 1];
  float4 r0 = {oacc[0][0] * il0, oacc[0][1] * il0, oacc[0][2] * il0, oacc[0][3] * il0};
  float4 r1 = {oacc[1][0] * il1, oacc[1][1] * il1, oacc[1][2] * il1, oacc[1][3] * il1};
  size_t o0 = ((size_t)b * N_ + i0 + ty * 2) * H_ + h * HD_ + tx * 4;
  *(float4*)&attn_out[o0] = r0;
  *(float4*)&attn_out[o0 + H_] = r1;
}

extern "C" void kernel_launch(void* const* d_in, const int* in_sizes, int n_in,
                              void* d_out, int out_size, void* d_ws, size_t ws_size,
                              hipStream_t stream) {
  const float* x = (const float*)d_in[0];
  const float* distances = (const float*)d_in[1];
  const int* mask = (const int*)d_in[2];
  const float* widths = (const float*)d_in[3];
  const float* dp_w = (const float*)d_in[4];
  const float* dp_b = (const float*)d_in[5];
  const float* wq = (const float*)d_in[6];
  const float* bq = (const float*)d_in[7];
  const float* wk = (const float*)d_in[8];
  const float* bk = (const float*)d_in[9];
  const float* wv = (const float*)d_in[10];
  const float* bv = (const float*)d_in[11];
  const float* wo = (const float*)d_in[12];
  const float* bo = (const float*)d_in[13];
  const float* ln1_g = (const float*)d_in[14];
  const float* ln1_b = (const float*)d_in[15];
  const float* ln2_g = (const float*)d_in[16];
  const float* ln2_b = (const float*)d_in[17];
  const float* w1 = (const float*)d_in[18];
  const float* b1 = (const float*)d_in[19];
  const float* w2 = (const float*)d_in[20];
  const float* b2 = (const float*)d_in[21];
  float* out = (float*)d_out;
  float* ws = (float*)d_ws;

  const size_t M1 = (size_t)1 << 20;  // 1M floats
  float* xn = ws;            // BN x H
  float* qb = ws + 1 * M1;   // B,NH,N,HD
  float* kb = ws + 2 * M1;
  float* vb = ws + 3 * M1;
  float* ao = ws + 4 * M1;   // B,N,H
  float* x1 = ws + 5 * M1;   // B,N,H
  float* xn2 = ws + 6 * M1;  // B,N,H
  float* hbuf = ws + 7 * M1; // BN x 4H (4M floats)

  const int BN = B_ * N_;  // 2048

  ln_k<<<BN, 128, 0, stream>>>(x, ln1_g, ln1_b, xn);

  dim3 g512(H_ / BNt, BN / BM);  // (8, 32)
  gemm_k<EPI_QKV><<<g512, 256, 0, stream>>>(xn, wq, bq, nullptr, qb, BN, H_, H_);
  gemm_k<EPI_QKV><<<g512, 256, 0, stream>>>(xn, wk, bk, nullptr, kb, BN, H_, H_);
  gemm_k<EPI_QKV><<<g512, 256, 0, stream>>>(xn, wv, bv, nullptr, vb, BN, H_, H_);

  attn_k<<<dim3(N_ / QT, NH_, B_), 256, 0, stream>>>(qb, kb, vb, distances, mask,
                                                     widths, dp_w, dp_b, ao);

  gemm_k<EPI_RES><<<g512, 256, 0, stream>>>(ao, wo, bo, x, x1, BN, H_, H_);

  ln_k<<<BN, 128, 0, stream>>>(x1, ln2_g, ln2_b, xn2);

  dim3 gffn1(4 * H_ / BNt, BN / BM);  // (32, 32)
  gemm_k<EPI_GELU><<<gffn1, 256, 0, stream>>>(xn2, w1, b1, nullptr, hbuf, BN, 4 * H_, H_);

  gemm_k<EPI_RES><<<g512, 256, 0, stream>>>(hbuf, w2, b2, x1, out, BN, H_, 2048);
}

// Round 2
// 231.425 us; speedup vs baseline: 2.9586x; 2.9586x over previous
//
#include <hip/hip_runtime.h>
#include <hip/hip_bf16.h>
#include <math.h>

#define B_ 2
#define N_ 1024
#define H_ 512
#define NH_ 8
#define HD_ 64
#define G_ 50
#define TAB_ 1024
constexpr float MAXD = 10.0f;

typedef __attribute__((ext_vector_type(8))) short short8;
typedef __attribute__((ext_vector_type(4))) float f32x4;

__device__ inline ushort f2bf(float v) {
  __hip_bfloat16 h = __float2bfloat16(v);
  return *(ushort*)&h;
}
__device__ inline float bf2f(ushort u) {
  unsigned x = ((unsigned)u) << 16;
  return __uint_as_float(x);
}

// ---------------- LayerNorm (f32 in -> bf16 out) ----------------
__global__ __launch_bounds__(128) void ln_k(const float* __restrict__ x,
                                            const float* __restrict__ g,
                                            const float* __restrict__ b,
                                            ushort* __restrict__ out) {
  int row = blockIdx.x;
  const float* xr = x + (size_t)row * H_;
  int t = threadIdx.x;
  float4 v = *(const float4*)(xr + t * 4);
  float s = v.x + v.y + v.z + v.w;
  float sq = v.x * v.x + v.y * v.y + v.z * v.z + v.w * v.w;
  #pragma unroll
  for (int m = 1; m < 64; m <<= 1) {
    s += __shfl_xor(s, m, 64);
    sq += __shfl_xor(sq, m, 64);
  }
  __shared__ float red[2][2];
  int wid = t >> 6;
  if ((t & 63) == 0) { red[wid][0] = s; red[wid][1] = sq; }
  __syncthreads();
  s = red[0][0] + red[1][0];
  sq = red[0][1] + red[1][1];
  float mu = s * (1.0f / H_);
  float var = sq * (1.0f / H_) - mu * mu;
  float rs = rsqrtf(var + 1e-5f);
  float4 gg = *(const float4*)(g + t * 4);
  float4 bb = *(const float4*)(b + t * 4);
  ushort4 o;
  o.x = f2bf((v.x - mu) * rs * gg.x + bb.x);
  o.y = f2bf((v.y - mu) * rs * gg.y + bb.y);
  o.z = f2bf((v.z - mu) * rs * gg.z + bb.z);
  o.w = f2bf((v.w - mu) * rs * gg.w + bb.w);
  *(ushort4*)(out + (size_t)row * H_ + t * 4) = o;
}

// ---------------- Bias table: tab[t][h] = sum_g exp(-(d_t-c_g)^2/(2w^2)) w_gh + b_h ----
__global__ void tab_k(const float* __restrict__ widths, const float* __restrict__ dp_w,
                      const float* __restrict__ dp_b, float* __restrict__ tab) {
  int t = blockIdx.x * 256 + threadIdx.x;
  if (t > TAB_) return;
  float d = (float)t * (MAXD / TAB_);
  float acc[NH_];
  #pragma unroll
  for (int h = 0; h < NH_; ++h) acc[h] = dp_b[h];
  for (int g = 0; g < G_; ++g) {
    float c = (float)g * (MAXD / 49.0f);
    float w = widths[g];
    float diff = d - c;
    float e = expf(-diff * diff / (2.0f * w * w));
    #pragma unroll
    for (int h = 0; h < NH_; ++h) acc[h] += e * dp_w[g * NH_ + h];
  }
  #pragma unroll
  for (int h = 0; h < NH_; ++h) tab[t * NH_ + h] = acc[h];
}

// ---------------- Fill bias[b,h,i,j] (bf16) via table lerp ----------------
__global__ __launch_bounds__(256) void biasfill_k(const float* __restrict__ dist,
                                                  const float* __restrict__ tab,
                                                  ushort* __restrict__ bias) {
  int i = blockIdx.x, b = blockIdx.y;
  __shared__ float tl[(TAB_ + 1) * NH_];
  for (int p = threadIdx.x; p < (TAB_ + 1) * NH_; p += 256) tl[p] = tab[p];
  __syncthreads();
  const float* drow = dist + ((size_t)b * N_ + i) * N_;
  for (int j = threadIdx.x; j < N_; j += 256) {
    float u = drow[j] * ((float)TAB_ / MAXD);
    int i0 = (int)u;
    if (i0 > TAB_ - 1) i0 = TAB_ - 1;
    if (i0 < 0) i0 = 0;
    float f = u - (float)i0;
    const float* t0 = &tl[i0 * NH_];
    const float* t1 = t0 + NH_;
    #pragma unroll
    for (int h = 0; h < NH_; ++h) {
      float v = t0[h] + f * (t1[h] - t0[h]);
      bias[(((size_t)(b * NH_ + h)) * N_ + i) * N_ + j] = f2bf(v);
    }
  }
}

// ---------------- Transpose+convert: src f32 [R][C] -> dst bf16 [C][R] ----------------
__global__ __launch_bounds__(256) void transp_k(const float* s0, const float* s1,
                                                const float* s2, const float* s3,
                                                ushort* __restrict__ dst, int R, int C) {
  const float* src = (blockIdx.z == 0) ? s0 : (blockIdx.z == 1) ? s1
                   : (blockIdx.z == 2) ? s2 : s3;
  ushort* d = dst + (size_t)blockIdx.z * R * C;
  __shared__ float tile[32][33];
  int t = threadIdx.x;
  int r0 = blockIdx.y * 32, c0 = blockIdx.x * 32;
  int rr = t >> 5, cc = t & 31;
  #pragma unroll
  for (int p = 0; p < 4; ++p)
    tile[rr + p * 8][cc] = src[(size_t)(r0 + rr + p * 8) * C + c0 + cc];
  __syncthreads();
  #pragma unroll
  for (int p = 0; p < 4; ++p)
    d[(size_t)(c0 + rr + p * 8) * R + r0 + cc] = f2bf(tile[cc][rr + p * 8]);
}

// ---------------- bf16 MFMA GEMM: C = A(MxK) @ Bt(NxK)^T + bias, epilogues ----------
enum { EPI_QKV = 1, EPI_RES = 2, EPI_GELU = 3 };

template <int BM, int BN, int EPI>
__global__ __launch_bounds__(256) void mfma_gemm(const ushort* __restrict__ A,
                                                 const ushort* __restrict__ Bt,
                                                 const float* __restrict__ b0,
                                                 const float* __restrict__ b1,
                                                 const float* __restrict__ b2,
                                                 const float* __restrict__ resid,
                                                 void* __restrict__ outv,
                                                 int K, int Nc) {
  __shared__ ushort As[BM * 32];
  __shared__ ushort Bs[BN * 32];
  int t = threadIdx.x;
  int z = blockIdx.z;
  const ushort* Bz = Bt + (size_t)z * Nc * K;
  const float* bias = (z == 0) ? b0 : (z == 1) ? b1 : b2;
  int m0 = blockIdx.y * BM, n0 = blockIdx.x * BN;
  int lane = t & 63, w = t >> 6, wr = w >> 1, wc = w & 1;
  int lrow = lane & 15, lkg = lane >> 4;
  constexpr int NFM = BM / 32, NFN = BN / 32;
  f32x4 acc[NFM][NFN] = {};
  for (int kt = 0; kt < K; kt += 32) {
    __syncthreads();
    {
      int kg = t & 3;
      for (int r = t >> 2; r < BM; r += 64) {
        int kgs = kg ^ ((r >> 1) & 3);
        *(short8*)&As[r * 32 + kgs * 8] =
            *(const short8*)&A[(size_t)(m0 + r) * K + kt + kg * 8];
      }
      for (int r = t >> 2; r < BN; r += 64) {
        int kgs = kg ^ ((r >> 1) & 3);
        *(short8*)&Bs[r * 32 + kgs * 8] =
            *(const short8*)&Bz[(size_t)(n0 + r) * K + kt + kg * 8];
      }
    }
    __syncthreads();
    short8 af[NFM], bfr[NFN];
    #pragma unroll
    for (int fm = 0; fm < NFM; ++fm) {
      int r = wr * (BM / 2) + fm * 16 + lrow;
      int kg = lkg ^ ((r >> 1) & 3);
      af[fm] = *(const short8*)&As[r * 32 + kg * 8];
    }
    #pragma unroll
    for (int fn = 0; fn < NFN; ++fn) {
      int r = wc * (BN / 2) + fn * 16 + lrow;
      int kg = lkg ^ ((r >> 1) & 3);
      bfr[fn] = *(const short8*)&Bs[r * 32 + kg * 8];
    }
    #pragma unroll
    for (int fm = 0; fm < NFM; ++fm)
      #pragma unroll
      for (int fn = 0; fn < NFN; ++fn)
        acc[fm][fn] = __builtin_amdgcn_mfma_f32_16x16x32_bf16(af[fm], bfr[fn],
                                                              acc[fm][fn], 0, 0, 0);
  }
  int rbase = (lane >> 4) * 4;
  #pragma unroll
  for (int fm = 0; fm < NFM; ++fm) {
    #pragma unroll
    for (int fn = 0; fn < NFN; ++fn) {
      #pragma unroll
      for (int j = 0; j < 4; ++j) {
        int row = m0 + wr * (BM / 2) + fm * 16 + rbase + j;
        int col = n0 + wc * (BN / 2) + fn * 16 + lrow;
        float v = acc[fm][fn][j] + bias[col];
        if constexpr (EPI == EPI_QKV) {
          float* q = (float*)outv + (size_t)z * (1 << 20);
          int bb = row >> 10, n = row & (N_ - 1);
          int h = col >> 6, d = col & 63;
          q[(((size_t)(bb * NH_ + h)) * N_ + n) * HD_ + d] = v;
        } else if constexpr (EPI == EPI_RES) {
          ((float*)outv)[(size_t)row * Nc + col] =
              resid[(size_t)row * Nc + col] + v;
        } else {  // GELU -> bf16
          ((ushort*)outv)[(size_t)row * Nc + col] =
              f2bf(0.5f * v * (1.0f + erff(v * 0.70710678118654752f)));
        }
      }
    }
  }
}

// ---------------- Fused flash attention, precomputed bf16 bias ----------------
constexpr int QT = 32, KT = 64;
__global__ __launch_bounds__(256) void attn_k(
    const float* __restrict__ q, const float* __restrict__ k, const float* __restrict__ v,
    const ushort* __restrict__ bias, const int* __restrict__ mask,
    ushort* __restrict__ aout) {
  int qt = blockIdx.x, h = blockIdx.y, b = blockIdx.z;
  int i0 = qt * QT;
  __shared__ float qT[HD_][QT + 4];   // [d][qi]
  __shared__ float kT[HD_][KT + 4];   // [d][j]
  __shared__ float vS[KT][HD_ + 4];   // [j][d]
  __shared__ float sbuf[QT][KT + 4];  // [qi][j]
  __shared__ float pT[KT][QT + 4];    // [j][qi]
  __shared__ float mrow[QT], lrow[QT], arow[QT];
  int t = threadIdx.x;
  int tx = t & 15, ty = t >> 4;
  if (t < QT) { mrow[t] = -1e30f; lrow[t] = 0.f; }
  const size_t headoff = ((size_t)(b * NH_ + h)) * N_ * HD_;
  const float* qbase = q + headoff;
  const float* kbase = k + headoff;
  const float* vbase = v + headoff;
  const ushort* bbase = bias + ((size_t)(b * NH_ + h)) * N_ * N_;
  for (int idx = t; idx < QT * HD_; idx += 256) {
    int d = idx & 63, qi = idx >> 6;
    qT[d][qi] = qbase[(size_t)(i0 + qi) * HD_ + d];
  }
  float oacc[2][4] = {};
  for (int j0 = 0; j0 < N_; j0 += KT) {
    __syncthreads();
    for (int idx = t; idx < KT * HD_; idx += 256) {
      int d = idx & 63, j = idx >> 6;
      kT[d][j] = kbase[(size_t)(j0 + j) * HD_ + d];
      vS[j][d] = vbase[(size_t)(j0 + j) * HD_ + d];
    }
    __syncthreads();
    float sa[2][4] = {};
    #pragma unroll 16
    for (int d = 0; d < HD_; ++d) {
      float2 qa = *(const float2*)&qT[d][ty * 2];
      float4 kb = *(const float4*)&kT[d][tx * 4];
      sa[0][0] = fmaf(qa.x, kb.x, sa[0][0]);
      sa[0][1] = fmaf(qa.x, kb.y, sa[0][1]);
      sa[0][2] = fmaf(qa.x, kb.z, sa[0][2]);
      sa[0][3] = fmaf(qa.x, kb.w, sa[0][3]);
      sa[1][0] = fmaf(qa.y, kb.x, sa[1][0]);
      sa[1][1] = fmaf(qa.y, kb.y, sa[1][1]);
      sa[1][2] = fmaf(qa.y, kb.z, sa[1][2]);
      sa[1][3] = fmaf(qa.y, kb.w, sa[1][3]);
    }
    #pragma unroll
    for (int i = 0; i < 2; ++i) {
      int qi = ty * 2 + i;
      ushort4 bv = *(const ushort4*)&bbase[(size_t)(i0 + qi) * N_ + j0 + tx * 4];
      float bvf[4] = {bf2f(bv.x), bf2f(bv.y), bf2f(bv.z), bf2f(bv.w)};
      #pragma unroll
      for (int j = 0; j < 4; ++j) {
        int jj = tx * 4 + j;
        float s = sa[i][j] * 0.125f + bvf[j];
        if (mask[b * N_ + j0 + jj] == 0) s = -1e9f;
        sbuf[qi][jj] = s;
      }
    }
    __syncthreads();
    {
      int rrow = t >> 3, c = t & 7;
      float sv[8];
      float tm = -1e30f;
      #pragma unroll
      for (int jj = 0; jj < 8; ++jj) {
        sv[jj] = sbuf[rrow][c * 8 + jj];
        tm = fmaxf(tm, sv[jj]);
      }
      #pragma unroll
      for (int m2 = 1; m2 < 8; m2 <<= 1) tm = fmaxf(tm, __shfl_xor(tm, m2, 64));
      float mold = mrow[rrow];
      float mnew = fmaxf(mold, tm);
      float alpha = __expf(mold - mnew);
      float psum = 0.f;
      #pragma unroll
      for (int jj = 0; jj < 8; ++jj) {
        float p = __expf(sv[jj] - mnew);
        pT[c * 8 + jj][rrow] = p;
        psum += p;
      }
      #pragma unroll
      for (int m2 = 1; m2 < 8; m2 <<= 1) psum += __shfl_xor(psum, m2, 64);
      if (c == 0) {
        lrow[rrow] = lrow[rrow] * alpha + psum;
        mrow[rrow] = mnew;
        arow[rrow] = alpha;
      }
    }
    __syncthreads();
    float a0 = arow[ty * 2], a1 = arow[ty * 2 + 1];
    #pragma unroll
    for (int j2 = 0; j2 < 4; ++j2) { oacc[0][j2] *= a0; oacc[1][j2] *= a1; }
    #pragma unroll 16
    for (int j = 0; j < KT; ++j) {
      float2 pa = *(const float2*)&pT[j][ty * 2];
      float4 vb4 = *(const float4*)&vS[j][tx * 4];
      oacc[0][0] = fmaf(pa.x, vb4.x, oacc[0][0]);
      oacc[0][1] = fmaf(pa.x, vb4.y, oacc[0][1]);
      oacc[0][2] = fmaf(pa.x, vb4.z, oacc[0][2]);
      oacc[0][3] = fmaf(pa.x, vb4.w, oacc[0][3]);
      oacc[1][0] = fmaf(pa.y, vb4.x, oacc[1][0]);
      oacc[1][1] = fmaf(pa.y, vb4.y, oacc[1][1]);
      oacc[1][2] = fmaf(pa.y, vb4.z, oacc[1][2]);
      oacc[1][3] = fmaf(pa.y, vb4.w, oacc[1][3]);
    }
  }
  float il0 = 1.0f / lrow[ty * 2];
  float il1 = 1.0f / lrow[ty * 2 + 1];
  size_t o0 = ((size_t)(b * N_ + i0 + ty * 2)) * H_ + h * HD_ + tx * 4;
  ushort4 r0 = {f2bf(oacc[0][0] * il0), f2bf(oacc[0][1] * il0),
                f2bf(oacc[0][2] * il0), f2bf(oacc[0][3] * il0)};
  ushort4 r1 = {f2bf(oacc[1][0] * il1), f2bf(oacc[1][1] * il1),
                f2bf(oacc[1][2] * il1), f2bf(oacc[1][3] * il1)};
  *(ushort4*)&aout[o0] = r0;
  *(ushort4*)&aout[o0 + H_] = r1;
}

extern "C" void kernel_launch(void* const* d_in, const int* in_sizes, int n_in,
                              void* d_out, int out_size, void* d_ws, size_t ws_size,
                              hipStream_t stream) {
  const float* x = (const float*)d_in[0];
  const float* distances = (const float*)d_in[1];
  const int* mask = (const int*)d_in[2];
  const float* widths = (const float*)d_in[3];
  const float* dp_w = (const float*)d_in[4];
  const float* dp_b = (const float*)d_in[5];
  const float* wq = (const float*)d_in[6];
  const float* bq = (const float*)d_in[7];
  const float* wk = (const float*)d_in[8];
  const float* bk = (const float*)d_in[9];
  const float* wv = (const float*)d_in[10];
  const float* bv = (const float*)d_in[11];
  const float* wo = (const float*)d_in[12];
  const float* bo = (const float*)d_in[13];
  const float* ln1_g = (const float*)d_in[14];
  const float* ln1_b = (const float*)d_in[15];
  const float* ln2_g = (const float*)d_in[16];
  const float* ln2_b = (const float*)d_in[17];
  const float* w1 = (const float*)d_in[18];
  const float* b1 = (const float*)d_in[19];
  const float* w2 = (const float*)d_in[20];
  const float* b2 = (const float*)d_in[21];
  float* out = (float*)d_out;
  float* wsf = (float*)d_ws;

  const size_t M1 = (size_t)1 << 20;
  float* qkv = wsf;                       // 3M f32: q,k,v [B,NH,N,HD]
  float* x1 = wsf + 3 * M1;               // 1M f32
  ushort* hbuf = (ushort*)(wsf + 4 * M1); // 4M bf16 (2M f32 slots)
  ushort* xn = (ushort*)(wsf + 6 * M1);   // 1M bf16
  ushort* xn2 = (ushort*)(wsf + 6 * M1 + M1 / 2);
  ushort* ao = (ushort*)(wsf + 7 * M1);
  ushort* wT4 = (ushort*)(wsf + 7 * M1 + M1 / 2);  // 4x 512x512 bf16
  ushort* w1T = (ushort*)(wsf + 8 * M1);           // [2048][512] bf16
  ushort* w2T = (ushort*)(wsf + 8 * M1 + M1 / 2);  // [512][2048] bf16
  float* tab = wsf + 9 * M1;                       // 8200 f32
  ushort* bias = (ushort*)(wsf + 9 * M1 + 16384);  // 16M bf16

  float* qb = qkv;
  float* kb = qkv + M1;
  float* vb = qkv + 2 * M1;

  transp_k<<<dim3(16, 16, 4), 256, 0, stream>>>(wq, wk, wv, wo, wT4, 512, 512);
  transp_k<<<dim3(64, 16, 1), 256, 0, stream>>>(w1, w1, w1, w1, w1T, 512, 2048);
  transp_k<<<dim3(16, 64, 1), 256, 0, stream>>>(w2, w2, w2, w2, w2T, 2048, 512);
  tab_k<<<5, 256, 0, stream>>>(widths, dp_w, dp_b, tab);
  biasfill_k<<<dim3(N_, B_), 256, 0, stream>>>(distances, tab, bias);

  ln_k<<<B_ * N_, 128, 0, stream>>>(x, ln1_g, ln1_b, xn);

  mfma_gemm<64, 64, EPI_QKV><<<dim3(8, 32, 3), 256, 0, stream>>>(
      xn, wT4, bq, bk, bv, nullptr, qkv, 512, 512);

  attn_k<<<dim3(N_ / QT, NH_, B_), 256, 0, stream>>>(qb, kb, vb, bias, mask, ao);

  mfma_gemm<64, 64, EPI_RES><<<dim3(8, 32, 1), 256, 0, stream>>>(
      ao, wT4 + (size_t)3 * 512 * 512, bo, bo, bo, x, x1, 512, 512);

  ln_k<<<B_ * N_, 128, 0, stream>>>(x1, ln2_g, ln2_b, xn2);

  mfma_gemm<128, 128, EPI_GELU><<<dim3(16, 16, 1), 256, 0, stream>>>(
      xn2, w1T, b1, b1, b1, nullptr, hbuf, 512, 2048);

  mfma_gemm<64, 64, EPI_RES><<<dim3(8, 32, 1), 256, 0, stream>>>(
      hbuf, w2T, b2, b2, b2, x1, out, 2048, 512);
}

// Round 3
// 149.425 us; speedup vs baseline: 4.5821x; 1.5488x over previous
//
#include <hip/hip_runtime.h>
#include <hip/hip_bf16.h>
#include <math.h>

#define B_ 2
#define N_ 1024
#define H_ 512
#define NH_ 8
#define HD_ 64
#define G_ 50
#define TAB_ 1024
constexpr float MAXD = 10.0f;

typedef __attribute__((ext_vector_type(8))) short short8;
typedef __attribute__((ext_vector_type(4))) float f32x4;

__device__ inline ushort f2bf(float v) {
  __hip_bfloat16 h = __float2bfloat16(v);
  return *(ushort*)&h;
}
__device__ inline float bf2f(ushort u) {
  unsigned x = ((unsigned)u) << 16;
  return __uint_as_float(x);
}

// ---------------- LayerNorm (f32 in -> bf16 out) ----------------
__global__ __launch_bounds__(128) void ln_k(const float* __restrict__ x,
                                            const float* __restrict__ g,
                                            const float* __restrict__ b,
                                            ushort* __restrict__ out) {
  int row = blockIdx.x;
  const float* xr = x + (size_t)row * H_;
  int t = threadIdx.x;
  float4 v = *(const float4*)(xr + t * 4);
  float s = v.x + v.y + v.z + v.w;
  float sq = v.x * v.x + v.y * v.y + v.z * v.z + v.w * v.w;
  #pragma unroll
  for (int m = 1; m < 64; m <<= 1) {
    s += __shfl_xor(s, m, 64);
    sq += __shfl_xor(sq, m, 64);
  }
  __shared__ float red[2][2];
  int wid = t >> 6;
  if ((t & 63) == 0) { red[wid][0] = s; red[wid][1] = sq; }
  __syncthreads();
  s = red[0][0] + red[1][0];
  sq = red[0][1] + red[1][1];
  float mu = s * (1.0f / H_);
  float var = sq * (1.0f / H_) - mu * mu;
  float rs = rsqrtf(var + 1e-5f);
  float4 gg = *(const float4*)(g + t * 4);
  float4 bb = *(const float4*)(b + t * 4);
  ushort4 o;
  o.x = f2bf((v.x - mu) * rs * gg.x + bb.x);
  o.y = f2bf((v.y - mu) * rs * gg.y + bb.y);
  o.z = f2bf((v.z - mu) * rs * gg.z + bb.z);
  o.w = f2bf((v.w - mu) * rs * gg.w + bb.w);
  *(ushort4*)(out + (size_t)row * H_ + t * 4) = o;
}

// ---------------- Bias table: tab[t][h] ----------------
__global__ void tab_k(const float* __restrict__ widths, const float* __restrict__ dp_w,
                      const float* __restrict__ dp_b, float* __restrict__ tab) {
  int t = blockIdx.x * 256 + threadIdx.x;
  if (t > TAB_) return;
  float d = (float)t * (MAXD / TAB_);
  float acc[NH_];
  #pragma unroll
  for (int h = 0; h < NH_; ++h) acc[h] = dp_b[h];
  for (int g = 0; g < G_; ++g) {
    float c = (float)g * (MAXD / 49.0f);
    float w = widths[g];
    float diff = d - c;
    float e = expf(-diff * diff / (2.0f * w * w));
    #pragma unroll
    for (int h = 0; h < NH_; ++h) acc[h] += e * dp_w[g * NH_ + h];
  }
  #pragma unroll
  for (int h = 0; h < NH_; ++h) tab[t * NH_ + h] = acc[h];
}

// ---------------- Transpose+convert: src f32 [R][C] -> dst bf16 [C][R] ----------------
__global__ __launch_bounds__(256) void transp_k(const float* s0, const float* s1,
                                                const float* s2, const float* s3,
                                                ushort* __restrict__ dst, int R, int C) {
  const float* src = (blockIdx.z == 0) ? s0 : (blockIdx.z == 1) ? s1
                   : (blockIdx.z == 2) ? s2 : s3;
  ushort* d = dst + (size_t)blockIdx.z * R * C;
  __shared__ float tile[32][33];
  int t = threadIdx.x;
  int r0 = blockIdx.y * 32, c0 = blockIdx.x * 32;
  int rr = t >> 5, cc = t & 31;
  #pragma unroll
  for (int p = 0; p < 4; ++p)
    tile[rr + p * 8][cc] = src[(size_t)(r0 + rr + p * 8) * C + c0 + cc];
  __syncthreads();
  #pragma unroll
  for (int p = 0; p < 4; ++p)
    d[(size_t)(c0 + rr + p * 8) * R + r0 + cc] = f2bf(tile[cc][rr + p * 8]);
}

// ---------------- bf16 MFMA GEMM: C = A(MxK) @ Bt(NxK)^T + bias, epilogues ----------
enum { EPI_QKV = 1, EPI_RES = 2, EPI_GELU = 3 };

template <int BM, int BN, int EPI>
__global__ __launch_bounds__(256) void mfma_gemm(const ushort* __restrict__ A,
                                                 const ushort* __restrict__ Bt,
                                                 const float* __restrict__ b0,
                                                 const float* __restrict__ b1,
                                                 const float* __restrict__ b2,
                                                 const float* __restrict__ resid,
                                                 void* __restrict__ outv,
                                                 int K, int Nc) {
  __shared__ ushort As[BM * 32];
  __shared__ ushort Bs[BN * 32];
  int t = threadIdx.x;
  int z = blockIdx.z;
  const ushort* Bz = Bt + (size_t)z * Nc * K;
  const float* bias = (z == 0) ? b0 : (z == 1) ? b1 : b2;
  int m0 = blockIdx.y * BM, n0 = blockIdx.x * BN;
  int lane = t & 63, w = t >> 6, wr = w >> 1, wc = w & 1;
  int lrow = lane & 15, lkg = lane >> 4;
  constexpr int NFM = BM / 32, NFN = BN / 32;
  f32x4 acc[NFM][NFN] = {};
  for (int kt = 0; kt < K; kt += 32) {
    __syncthreads();
    {
      int kg = t & 3;
      for (int r = t >> 2; r < BM; r += 64) {
        int kgs = kg ^ ((r >> 1) & 3);
        *(short8*)&As[r * 32 + kgs * 8] =
            *(const short8*)&A[(size_t)(m0 + r) * K + kt + kg * 8];
      }
      for (int r = t >> 2; r < BN; r += 64) {
        int kgs = kg ^ ((r >> 1) & 3);
        *(short8*)&Bs[r * 32 + kgs * 8] =
            *(const short8*)&Bz[(size_t)(n0 + r) * K + kt + kg * 8];
      }
    }
    __syncthreads();
    short8 af[NFM], bfr[NFN];
    #pragma unroll
    for (int fm = 0; fm < NFM; ++fm) {
      int r = wr * (BM / 2) + fm * 16 + lrow;
      int kg = lkg ^ ((r >> 1) & 3);
      af[fm] = *(const short8*)&As[r * 32 + kg * 8];
    }
    #pragma unroll
    for (int fn = 0; fn < NFN; ++fn) {
      int r = wc * (BN / 2) + fn * 16 + lrow;
      int kg = lkg ^ ((r >> 1) & 3);
      bfr[fn] = *(const short8*)&Bs[r * 32 + kg * 8];
    }
    #pragma unroll
    for (int fm = 0; fm < NFM; ++fm)
      #pragma unroll
      for (int fn = 0; fn < NFN; ++fn)
        acc[fm][fn] = __builtin_amdgcn_mfma_f32_16x16x32_bf16(af[fm], bfr[fn],
                                                              acc[fm][fn], 0, 0, 0);
  }
  int rbase = (lane >> 4) * 4;
  #pragma unroll
  for (int fm = 0; fm < NFM; ++fm) {
    #pragma unroll
    for (int fn = 0; fn < NFN; ++fn) {
      #pragma unroll
      for (int j = 0; j < 4; ++j) {
        int row = m0 + wr * (BM / 2) + fm * 16 + rbase + j;
        int col = n0 + wc * (BN / 2) + fn * 16 + lrow;
        float v = acc[fm][fn][j] + bias[col];
        if constexpr (EPI == EPI_QKV) {
          ushort* q = (ushort*)outv + (size_t)z * (1 << 20);
          int bb = row >> 10, n = row & (N_ - 1);
          int h = col >> 6, d = col & 63;
          q[(((size_t)(bb * NH_ + h)) * N_ + n) * HD_ + d] = f2bf(v);
        } else if constexpr (EPI == EPI_RES) {
          ((float*)outv)[(size_t)row * Nc + col] =
              resid[(size_t)row * Nc + col] + v;
        } else {  // GELU -> bf16
          ((ushort*)outv)[(size_t)row * Nc + col] =
              f2bf(0.5f * v * (1.0f + erff(v * 0.70710678118654752f)));
        }
      }
    }
  }
}

// ---------------- MFMA flash attention with inline table-lerp bias ----------------
constexpr int QT = 64, KT = 64, NT = N_ / KT;

__global__ __launch_bounds__(256) void attn_k(
    const ushort* __restrict__ q, const ushort* __restrict__ k,
    const ushort* __restrict__ v, const float* __restrict__ dist,
    const int* __restrict__ mask, const float* __restrict__ tab,
    ushort* __restrict__ aout) {
  int qt = blockIdx.x, h = blockIdx.y, b = blockIdx.z;
  int i0 = qt * QT;
  __shared__ ushort Ks[KT * 64];      // [j][d] chunk-swizzled
  __shared__ ushort Vt[64 * KT];      // [d][j] chunk-swizzled
  __shared__ ushort Ps[4][16 * 64];   // per-warp P[q][j] chunk-swizzled
  __shared__ float tl[TAB_ + 1];
  __shared__ float mfl[N_];
  int t = threadIdx.x;
  int lane = t & 63, w = t >> 6;
  int l = lane & 15, g = lane >> 4;

  for (int i = t; i <= TAB_; i += 256) tl[i] = tab[i * NH_ + h];
  for (int i = t; i < N_; i += 256) mfl[i] = (mask[b * N_ + i] == 0) ? -1e9f : 0.0f;

  const size_t ho = ((size_t)(b * NH_ + h)) * N_ * HD_;
  const ushort* qb = q + ho;
  const ushort* kb = k + ho;
  const ushort* vb = v + ho;

  // Q fragments (A-operand): row = lane&15, k-chunk = (lane>>4)*8
  int qrow = i0 + w * 16 + l;
  short8 qf[2];
  qf[0] = *(const short8*)&qb[(size_t)qrow * 64 + g * 8];
  qf[1] = *(const short8*)&qb[(size_t)qrow * 64 + 32 + g * 8];

  int c2 = t & 7, jr = t >> 3;  // staging: chunk 0..7, rows 0..31 (+32)

  auto stK = [&](short8 val, int j2) {
    int idx = j2 * 64 + ((c2 >> 2) << 5) + (((c2 & 3) ^ ((j2 >> 1) & 3)) << 3);
    *(short8*)&Ks[idx] = val;
  };
  auto stV = [&](short8 val, int j2) {
    #pragma unroll
    for (int i = 0; i < 8; ++i) {
      int d = c2 * 8 + i;
      int idx = d * 64 + ((j2 >> 5) << 5) + ((((j2 >> 3) & 3) ^ ((d >> 1) & 3)) << 3) + (j2 & 7);
      Vt[idx] = (ushort)val[i];
    }
  };

  {  // stage tile 0
    short8 a0 = *(const short8*)&kb[(size_t)jr * 64 + c2 * 8];
    short8 a1 = *(const short8*)&kb[(size_t)(jr + 32) * 64 + c2 * 8];
    short8 a2 = *(const short8*)&vb[(size_t)jr * 64 + c2 * 8];
    short8 a3 = *(const short8*)&vb[(size_t)(jr + 32) * 64 + c2 * 8];
    stK(a0, jr); stK(a1, jr + 32); stV(a2, jr); stV(a3, jr + 32);
  }
  __syncthreads();

  float m_[4] = {-1e30f, -1e30f, -1e30f, -1e30f};
  float l_[4] = {0.f, 0.f, 0.f, 0.f};
  f32x4 acc[4] = {{0,0,0,0},{0,0,0,0},{0,0,0,0},{0,0,0,0}};

  for (int tt = 0; tt < NT; ++tt) {
    const int j0 = tt * KT;
    short8 p0, p1, p2, p3;
    if (tt + 1 < NT) {
      const ushort* kn = kb + (size_t)(j0 + KT) * 64;
      const ushort* vn = vb + (size_t)(j0 + KT) * 64;
      p0 = *(const short8*)&kn[(size_t)jr * 64 + c2 * 8];
      p1 = *(const short8*)&kn[(size_t)(jr + 32) * 64 + c2 * 8];
      p2 = *(const short8*)&vn[(size_t)jr * 64 + c2 * 8];
      p3 = *(const short8*)&vn[(size_t)(jr + 32) * 64 + c2 * 8];
    }
    // dist loads for this tile
    float dd[4][4];
    const float* dbase = dist + (size_t)b * N_ * N_ +
                         (size_t)(i0 + w * 16 + 4 * g) * N_ + j0 + l;
    #pragma unroll
    for (int reg = 0; reg < 4; ++reg)
      #pragma unroll
      for (int fj = 0; fj < 4; ++fj)
        dd[reg][fj] = dbase[(size_t)reg * N_ + fj * 16];
    // S = Q K^T
    f32x4 sa[4] = {{0,0,0,0},{0,0,0,0},{0,0,0,0},{0,0,0,0}};
    #pragma unroll
    for (int dblk = 0; dblk < 2; ++dblk)
      #pragma unroll
      for (int fj = 0; fj < 4; ++fj) {
        int j2 = fj * 16 + l;
        short8 kf = *(const short8*)&Ks[j2 * 64 + (dblk << 5) + ((g ^ ((j2 >> 1) & 3)) << 3)];
        sa[fj] = __builtin_amdgcn_mfma_f32_16x16x32_bf16(qf[dblk], kf, sa[fj], 0, 0, 0);
      }
    // bias + mask + online softmax (rows live in (g,reg); reduce over 16 lanes)
    float al_[4];
    #pragma unroll
    for (int reg = 0; reg < 4; ++reg) {
      float svr[4];
      #pragma unroll
      for (int fj = 0; fj < 4; ++fj) {
        float u = dd[reg][fj] * ((float)TAB_ / MAXD);
        int it = (int)u;
        it = it < 0 ? 0 : (it > TAB_ - 1 ? TAB_ - 1 : it);
        float f = u - (float)it;
        float t0v = tl[it], t1v = tl[it + 1];
        svr[fj] = fmaf(sa[fj][reg], 0.125f, fmaf(f, t1v - t0v, t0v)) +
                  mfl[j0 + fj * 16 + l];
      }
      float rm = fmaxf(fmaxf(svr[0], svr[1]), fmaxf(svr[2], svr[3]));
      rm = fmaxf(rm, __shfl_xor(rm, 1, 64));
      rm = fmaxf(rm, __shfl_xor(rm, 2, 64));
      rm = fmaxf(rm, __shfl_xor(rm, 4, 64));
      rm = fmaxf(rm, __shfl_xor(rm, 8, 64));
      float mn = fmaxf(m_[reg], rm);
      float al = __expf(m_[reg] - mn);
      m_[reg] = mn;
      al_[reg] = al;
      float ps = 0.f;
      int qlq = 4 * g + reg;
      int rowoff = qlq * 64;
      int swz = (qlq >> 1) & 3;
      #pragma unroll
      for (int fj = 0; fj < 4; ++fj) {
        float p = __expf(svr[fj] - mn);
        ps += p;
        int kg = ((fj & 1) << 1) | (l >> 3);
        Ps[w][rowoff + ((fj >> 1) << 5) + ((kg ^ swz) << 3) + (l & 7)] = f2bf(p);
      }
      ps += __shfl_xor(ps, 1, 64);
      ps += __shfl_xor(ps, 2, 64);
      ps += __shfl_xor(ps, 4, 64);
      ps += __shfl_xor(ps, 8, 64);
      l_[reg] = l_[reg] * al + ps;
    }
    // rescale O
    #pragma unroll
    for (int fd = 0; fd < 4; ++fd)
      #pragma unroll
      for (int reg = 0; reg < 4; ++reg) acc[fd][reg] *= al_[reg];
    // O += P V  (P A-frags from per-warp LDS, V^T B-frags)
    #pragma unroll
    for (int jj = 0; jj < 2; ++jj) {
      short8 pa = *(const short8*)&Ps[w][l * 64 + (jj << 5) + ((g ^ ((l >> 1) & 3)) << 3)];
      #pragma unroll
      for (int fd = 0; fd < 4; ++fd) {
        int d2 = fd * 16 + l;
        short8 vf = *(const short8*)&Vt[d2 * 64 + (jj << 5) + ((g ^ ((d2 >> 1) & 3)) << 3)];
        acc[fd] = __builtin_amdgcn_mfma_f32_16x16x32_bf16(pa, vf, acc[fd], 0, 0, 0);
      }
    }
    __syncthreads();
    if (tt + 1 < NT) { stK(p0, jr); stK(p1, jr + 32); stV(p2, jr); stV(p3, jr + 32); }
    __syncthreads();
  }
  // epilogue
  float il[4];
  #pragma unroll
  for (int reg = 0; reg < 4; ++reg) il[reg] = 1.0f / l_[reg];
  ushort* ob = aout + ((size_t)(b * N_ + i0 + w * 16 + 4 * g)) * H_ + h * HD_ + l;
  #pragma unroll
  for (int reg = 0; reg < 4; ++reg)
    #pragma unroll
    for (int fd = 0; fd < 4; ++fd)
      ob[(size_t)reg * H_ + fd * 16] = f2bf(acc[fd][reg] * il[reg]);
}

extern "C" void kernel_launch(void* const* d_in, const int* in_sizes, int n_in,
                              void* d_out, int out_size, void* d_ws, size_t ws_size,
                              hipStream_t stream) {
  const float* x = (const float*)d_in[0];
  const float* distances = (const float*)d_in[1];
  const int* mask = (const int*)d_in[2];
  const float* widths = (const float*)d_in[3];
  const float* dp_w = (const float*)d_in[4];
  const float* dp_b = (const float*)d_in[5];
  const float* wq = (const float*)d_in[6];
  const float* bq = (const float*)d_in[7];
  const float* wk = (const float*)d_in[8];
  const float* bk = (const float*)d_in[9];
  const float* wv = (const float*)d_in[10];
  const float* bv = (const float*)d_in[11];
  const float* wo = (const float*)d_in[12];
  const float* bo = (const float*)d_in[13];
  const float* ln1_g = (const float*)d_in[14];
  const float* ln1_b = (const float*)d_in[15];
  const float* ln2_g = (const float*)d_in[16];
  const float* ln2_b = (const float*)d_in[17];
  const float* w1 = (const float*)d_in[18];
  const float* b1 = (const float*)d_in[19];
  const float* w2 = (const float*)d_in[20];
  const float* b2 = (const float*)d_in[21];
  float* out = (float*)d_out;
  float* wsf = (float*)d_ws;

  const size_t M1 = (size_t)1 << 20;
  ushort* qkvb = (ushort*)wsf;                       // 3M bf16 (1.5 M1)
  float* x1 = wsf + 2 * M1;                          // 1M f32
  ushort* hbuf = (ushort*)(wsf + 3 * M1);            // 4M bf16 (2 M1)
  ushort* xn = (ushort*)(wsf + 5 * M1);              // 1M bf16
  ushort* xn2 = (ushort*)(wsf + 5 * M1 + M1 / 2);
  ushort* ao = (ushort*)(wsf + 6 * M1);              // 1M bf16
  ushort* wT4 = (ushort*)(wsf + 6 * M1 + M1 / 2);    // 4x 512x512 bf16
  ushort* w1T = (ushort*)(wsf + 7 * M1);             // [2048][512] bf16
  ushort* w2T = (ushort*)(wsf + 7 * M1 + M1 / 2);    // [512][2048] bf16
  float* tab = wsf + 8 * M1;                         // 8200 f32

  transp_k<<<dim3(16, 16, 4), 256, 0, stream>>>(wq, wk, wv, wo, wT4, 512, 512);
  transp_k<<<dim3(64, 16, 1), 256, 0, stream>>>(w1, w1, w1, w1, w1T, 512, 2048);
  transp_k<<<dim3(16, 64, 1), 256, 0, stream>>>(w2, w2, w2, w2, w2T, 2048, 512);
  tab_k<<<5, 256, 0, stream>>>(widths, dp_w, dp_b, tab);

  ln_k<<<B_ * N_, 128, 0, stream>>>(x, ln1_g, ln1_b, xn);

  mfma_gemm<64, 64, EPI_QKV><<<dim3(8, 32, 3), 256, 0, stream>>>(
      xn, wT4, bq, bk, bv, nullptr, qkvb, 512, 512);

  attn_k<<<dim3(N_ / QT, NH_, B_), 256, 0, stream>>>(
      qkvb, qkvb + M1, qkvb + 2 * M1, distances, mask, tab, ao);

  mfma_gemm<64, 64, EPI_RES><<<dim3(8, 32, 1), 256, 0, stream>>>(
      ao, wT4 + (size_t)3 * 512 * 512, bo, bo, bo, x, x1, 512, 512);

  ln_k<<<B_ * N_, 128, 0, stream>>>(x1, ln2_g, ln2_b, xn2);

  mfma_gemm<128, 128, EPI_GELU><<<dim3(16, 16, 1), 256, 0, stream>>>(
      xn2, w1T, b1, b1, b1, nullptr, hbuf, 512, 2048);

  mfma_gemm<64, 64, EPI_RES><<<dim3(8, 32, 1), 256, 0, stream>>>(
      hbuf, w2T, b2, b2, b2, x1, out, 2048, 512);
}

// Round 5
// 137.209 us; speedup vs baseline: 4.9901x; 1.0890x over previous
//
#include <hip/hip_runtime.h>
#include <hip/hip_bf16.h>
#include <math.h>

#define B_ 2
#define N_ 1024
#define H_ 512
#define NH_ 8
#define HD_ 64
#define G_ 50
#define TAB_ 1024
constexpr float MAXD = 10.0f;

typedef __attribute__((ext_vector_type(8))) short short8;
typedef __attribute__((ext_vector_type(4))) float f32x4;

__device__ inline ushort f2bf(float v) {
  __hip_bfloat16 h = __float2bfloat16(v);
  return *(ushort*)&h;
}
__device__ inline float bf2f(ushort u) {
  unsigned x = ((unsigned)u) << 16;
  return __uint_as_float(x);
}

// ---------------- LayerNorm (f32 in -> bf16 out) ----------------
__global__ __launch_bounds__(128) void ln_k(const float* __restrict__ x,
                                            const float* __restrict__ g,
                                            const float* __restrict__ b,
                                            ushort* __restrict__ out) {
  int row = blockIdx.x;
  const float* xr = x + (size_t)row * H_;
  int t = threadIdx.x;
  float4 v = *(const float4*)(xr + t * 4);
  float s = v.x + v.y + v.z + v.w;
  float sq = v.x * v.x + v.y * v.y + v.z * v.z + v.w * v.w;
  #pragma unroll
  for (int m = 1; m < 64; m <<= 1) {
    s += __shfl_xor(s, m, 64);
    sq += __shfl_xor(sq, m, 64);
  }
  __shared__ float red[2][2];
  int wid = t >> 6;
  if ((t & 63) == 0) { red[wid][0] = s; red[wid][1] = sq; }
  __syncthreads();
  s = red[0][0] + red[1][0];
  sq = red[0][1] + red[1][1];
  float mu = s * (1.0f / H_);
  float var = sq * (1.0f / H_) - mu * mu;
  float rs = rsqrtf(var + 1e-5f);
  float4 gg = *(const float4*)(g + t * 4);
  float4 bb = *(const float4*)(b + t * 4);
  ushort4 o;
  o.x = f2bf((v.x - mu) * rs * gg.x + bb.x);
  o.y = f2bf((v.y - mu) * rs * gg.y + bb.y);
  o.z = f2bf((v.z - mu) * rs * gg.z + bb.z);
  o.w = f2bf((v.w - mu) * rs * gg.w + bb.w);
  *(ushort4*)(out + (size_t)row * H_ + t * 4) = o;
}

// ---------------- Bias table: tabf[t][h] ----------------
__global__ void tab_k(const float* __restrict__ widths, const float* __restrict__ dp_w,
                      const float* __restrict__ dp_b, float* __restrict__ tab) {
  int t = blockIdx.x * 256 + threadIdx.x;
  if (t > TAB_) return;
  float d = (float)t * (MAXD / TAB_);
  float acc[NH_];
  #pragma unroll
  for (int h = 0; h < NH_; ++h) acc[h] = dp_b[h];
  for (int g = 0; g < G_; ++g) {
    float c = (float)g * (MAXD / 49.0f);
    float w = widths[g];
    float diff = d - c;
    float e = expf(-diff * diff / (2.0f * w * w));
    #pragma unroll
    for (int h = 0; h < NH_; ++h) acc[h] += e * dp_w[g * NH_ + h];
  }
  #pragma unroll
  for (int h = 0; h < NH_; ++h) tab[t * NH_ + h] = acc[h];
}

// tab2[h][t] = (tabf[t][h], tabf[t+1][h])
__global__ void tab2_k(const float* __restrict__ tabf, float2* __restrict__ tab2) {
  int i = blockIdx.x * 256 + threadIdx.x;
  if (i >= NH_ * (TAB_ + 1)) return;
  int h = i / (TAB_ + 1), t = i % (TAB_ + 1);
  int t1 = t < TAB_ ? t + 1 : t;
  tab2[i] = make_float2(tabf[t * NH_ + h], tabf[t1 * NH_ + h]);
}

// ---------------- Transpose+convert: src f32 [R][C] -> dst bf16 [C][R] ----------------
__global__ __launch_bounds__(256) void transp_k(const float* s0, const float* s1,
                                                const float* s2, const float* s3,
                                                ushort* __restrict__ dst, int R, int C) {
  const float* src = (blockIdx.z == 0) ? s0 : (blockIdx.z == 1) ? s1
                   : (blockIdx.z == 2) ? s2 : s3;
  ushort* d = dst + (size_t)blockIdx.z * R * C;
  __shared__ float tile[32][33];
  int t = threadIdx.x;
  int r0 = blockIdx.y * 32, c0 = blockIdx.x * 32;
  int rr = t >> 5, cc = t & 31;
  #pragma unroll
  for (int p = 0; p < 4; ++p)
    tile[rr + p * 8][cc] = src[(size_t)(r0 + rr + p * 8) * C + c0 + cc];
  __syncthreads();
  #pragma unroll
  for (int p = 0; p < 4; ++p)
    d[(size_t)(c0 + rr + p * 8) * R + r0 + cc] = f2bf(tile[cc][rr + p * 8]);
}

// ---------------- bf16 MFMA GEMM with register double-buffer ----------
enum { EPI_QKV = 1, EPI_RES = 2, EPI_GELU = 3 };

template <int BM, int BN, int EPI>
__global__ __launch_bounds__(256) void mfma_gemm(const ushort* __restrict__ A,
                                                 const ushort* __restrict__ Bt,
                                                 const float* __restrict__ b0,
                                                 const float* __restrict__ b1,
                                                 const float* __restrict__ b2,
                                                 const float* __restrict__ resid,
                                                 void* __restrict__ outv,
                                                 int K, int Nc) {
  __shared__ ushort As[BM * 32];
  __shared__ ushort Bs[BN * 32];
  int t = threadIdx.x;
  int z = blockIdx.z;
  const ushort* Bz = Bt + (size_t)z * Nc * K;
  const float* bias = (z == 0) ? b0 : (z == 1) ? b1 : b2;
  int m0 = blockIdx.y * BM, n0 = blockIdx.x * BN;
  int lane = t & 63, w = t >> 6, wr = w >> 1, wc = w & 1;
  int lrow = lane & 15, lkg = lane >> 4;
  constexpr int NFM = BM / 32, NFN = BN / 32;
  constexpr int AL = BM / 64, BL = BN / 64;
  f32x4 acc[NFM][NFN] = {};
  int kg = t & 3, r0 = t >> 2;

  short8 raA[AL], rbA[BL], raB[AL], rbB[BL];
  auto loadT = [&](int kt, short8 (&la)[AL], short8 (&lb)[BL]) {
    #pragma unroll
    for (int p = 0; p < AL; ++p)
      la[p] = *(const short8*)&A[(size_t)(m0 + r0 + p * 64) * K + kt + kg * 8];
    #pragma unroll
    for (int p = 0; p < BL; ++p)
      lb[p] = *(const short8*)&Bz[(size_t)(n0 + r0 + p * 64) * K + kt + kg * 8];
  };
  auto storeT = [&](short8 (&la)[AL], short8 (&lb)[BL]) {
    #pragma unroll
    for (int p = 0; p < AL; ++p) {
      int r = r0 + p * 64;
      int kgs = kg ^ ((r >> 1) & 3);
      *(short8*)&As[r * 32 + kgs * 8] = la[p];
    }
    #pragma unroll
    for (int p = 0; p < BL; ++p) {
      int r = r0 + p * 64;
      int kgs = kg ^ ((r >> 1) & 3);
      *(short8*)&Bs[r * 32 + kgs * 8] = lb[p];
    }
  };
  auto compute = [&]() {
    short8 af[NFM], bfr[NFN];
    #pragma unroll
    for (int fm = 0; fm < NFM; ++fm) {
      int r = wr * (BM / 2) + fm * 16 + lrow;
      int kgx = lkg ^ ((r >> 1) & 3);
      af[fm] = *(const short8*)&As[r * 32 + kgx * 8];
    }
    #pragma unroll
    for (int fn = 0; fn < NFN; ++fn) {
      int r = wc * (BN / 2) + fn * 16 + lrow;
      int kgx = lkg ^ ((r >> 1) & 3);
      bfr[fn] = *(const short8*)&Bs[r * 32 + kgx * 8];
    }
    #pragma unroll
    for (int fm = 0; fm < NFM; ++fm)
      #pragma unroll
      for (int fn = 0; fn < NFN; ++fn)
        acc[fm][fn] = __builtin_amdgcn_mfma_f32_16x16x32_bf16(af[fm], bfr[fn],
                                                              acc[fm][fn], 0, 0, 0);
  };

  loadT(0, raA, rbA);
  for (int kt = 0; kt < K; kt += 64) {
    __syncthreads();
    storeT(raA, rbA);
    __syncthreads();
    loadT(kt + 32, raB, rbB);
    compute();
    __syncthreads();
    storeT(raB, rbB);
    __syncthreads();
    if (kt + 64 < K) loadT(kt + 64, raA, rbA);
    compute();
  }

  int rbase = (lane >> 4) * 4;
  #pragma unroll
  for (int fm = 0; fm < NFM; ++fm) {
    #pragma unroll
    for (int fn = 0; fn < NFN; ++fn) {
      #pragma unroll
      for (int j = 0; j < 4; ++j) {
        int row = m0 + wr * (BM / 2) + fm * 16 + rbase + j;
        int col = n0 + wc * (BN / 2) + fn * 16 + lrow;
        float v = acc[fm][fn][j] + bias[col];
        if constexpr (EPI == EPI_QKV) {
          ushort* q = (ushort*)outv + (size_t)z * (1 << 20);
          int bb = row >> 10, n = row & (N_ - 1);
          int h = col >> 6, d = col & 63;
          q[(((size_t)(bb * NH_ + h)) * N_ + n) * HD_ + d] = f2bf(v);
        } else if constexpr (EPI == EPI_RES) {
          ((float*)outv)[(size_t)row * Nc + col] =
              resid[(size_t)row * Nc + col] + v;
        } else {  // GELU -> bf16
          ((ushort*)outv)[(size_t)row * Nc + col] =
              f2bf(0.5f * v * (1.0f + erff(v * 0.70710678118654752f)));
        }
      }
    }
  }
}

// ---------------- MFMA flash attention, j-split, LDS bias tile ----------------
constexpr int QT = 32, KT = 64, NJH = 2, NTH = N_ / (KT * NJH);  // 8 tiles/block

__global__ __launch_bounds__(128) void attn_k(
    const ushort* __restrict__ q, const ushort* __restrict__ k,
    const ushort* __restrict__ v, const float* __restrict__ dist,
    const int* __restrict__ mask, const float2* __restrict__ tab2g,
    float* __restrict__ Op, float2* __restrict__ ml) {
  int qt = blockIdx.x, h = blockIdx.y, z = blockIdx.z;
  int b = z >> 1, jh = z & 1;
  int i0 = qt * QT;
  int jbase = jh * (N_ / NJH);
  __shared__ ushort Ks[KT * 64];      // [j][d] chunk-swizzled
  __shared__ ushort Vt[64 * KT];      // [d][j] chunk-swizzled
  __shared__ ushort Bsb[QT * 68];     // bias tile [q][j], stride 68
  __shared__ ushort Ps[2][16 * 64];   // per-warp P chunk-swizzled
  __shared__ float2 tl2[TAB_ + 1];
  __shared__ float mfl[N_];
  int t = threadIdx.x;
  int lane = t & 63, w = t >> 6;
  int l = lane & 15, g = lane >> 4;

  for (int i = t; i <= TAB_; i += 128) tl2[i] = tab2g[h * (TAB_ + 1) + i];
  for (int i = t; i < N_; i += 128) mfl[i] = (mask[b * N_ + i] == 0) ? -1e9f : 0.0f;

  const size_t ho = ((size_t)(b * NH_ + h)) * N_ * HD_;
  const ushort* qb = q + ho;
  const ushort* kb = k + ho;
  const ushort* vb = v + ho;

  int qrow = i0 + w * 16 + l;
  short8 qf[2];
  qf[0] = *(const short8*)&qb[(size_t)qrow * 64 + g * 8];
  qf[1] = *(const short8*)&qb[(size_t)qrow * 64 + 32 + g * 8];

  int c2 = t & 7, jr = t >> 3;  // K/V staging: chunk c2 (0..7), row jr (0..15) + {0,16,32,48}
  int dr_r = t >> 2, dr_c = (t & 3) * 16;  // dist staging: row, col-base

  auto stK = [&](short8 val, int j2) {
    int idx = j2 * 64 + ((c2 >> 2) << 5) + (((c2 & 3) ^ ((j2 >> 1) & 3)) << 3);
    *(short8*)&Ks[idx] = val;
  };
  auto stV = [&](short8 val, int j2) {
    #pragma unroll
    for (int i = 0; i < 8; ++i) {
      int d = c2 * 8 + i;
      int idx = d * 64 + ((j2 >> 5) << 5) + ((((j2 >> 3) & 3) ^ ((d >> 1) & 3)) << 3) + (j2 & 7);
      Vt[idx] = (ushort)val[i];
    }
  };

  // --- prologue: load + stage tile 0 ---
  short8 k0a, k1a, v0a, v1a, k2a, k3a, v2a, v3a;
  f32x4 dda[4];
  {
    const ushort* kn = kb + (size_t)jbase * 64;
    const ushort* vn = vb + (size_t)jbase * 64;
    k0a = *(const short8*)&kn[(size_t)jr * 64 + c2 * 8];
    k1a = *(const short8*)&kn[(size_t)(jr + 16) * 64 + c2 * 8];
    k2a = *(const short8*)&kn[(size_t)(jr + 32) * 64 + c2 * 8];
    k3a = *(const short8*)&kn[(size_t)(jr + 48) * 64 + c2 * 8];
    v0a = *(const short8*)&vn[(size_t)jr * 64 + c2 * 8];
    v1a = *(const short8*)&vn[(size_t)(jr + 16) * 64 + c2 * 8];
    v2a = *(const short8*)&vn[(size_t)(jr + 32) * 64 + c2 * 8];
    v3a = *(const short8*)&vn[(size_t)(jr + 48) * 64 + c2 * 8];
    const float* db = dist + ((size_t)b * N_ + (i0 + dr_r)) * N_ + jbase + dr_c;
    #pragma unroll
    for (int p = 0; p < 4; ++p) dda[p] = *(const f32x4*)&db[p * 4];
  }
  __syncthreads();  // tl2 + mfl ready
  {
    stK(k0a, jr); stK(k1a, jr + 16); stK(k2a, jr + 32); stK(k3a, jr + 48);
    stV(v0a, jr); stV(v1a, jr + 16); stV(v2a, jr + 32); stV(v3a, jr + 48);
    #pragma unroll
    for (int p = 0; p < 4; ++p) {
      ushort4 ov;
      #pragma unroll
      for (int e = 0; e < 4; ++e) {
        int jcol = dr_c + p * 4 + e;
        float u = dda[p][e] * ((float)TAB_ / MAXD);
        int it = (int)u;
        it = it < 0 ? 0 : (it > TAB_ - 1 ? TAB_ - 1 : it);
        float f = u - (float)it;
        float2 tv = tl2[it];
        ((ushort*)&ov)[e] = f2bf(tv.x + f * (tv.y - tv.x) + mfl[jbase + jcol]);
      }
      *(ushort4*)&Bsb[dr_r * 68 + dr_c + p * 4] = ov;
    }
  }
  __syncthreads();

  float m_[4] = {-1e30f, -1e30f, -1e30f, -1e30f};
  float l_[4] = {0.f, 0.f, 0.f, 0.f};
  f32x4 acc[4] = {{0,0,0,0},{0,0,0,0},{0,0,0,0},{0,0,0,0}};

  for (int tt = 0; tt < NTH; ++tt) {
    const int j0 = jbase + tt * KT;
    if (tt + 1 < NTH) {
      const ushort* kn = kb + (size_t)(j0 + KT) * 64;
      const ushort* vn = vb + (size_t)(j0 + KT) * 64;
      k0a = *(const short8*)&kn[(size_t)jr * 64 + c2 * 8];
      k1a = *(const short8*)&kn[(size_t)(jr + 16) * 64 + c2 * 8];
      k2a = *(const short8*)&kn[(size_t)(jr + 32) * 64 + c2 * 8];
      k3a = *(const short8*)&kn[(size_t)(jr + 48) * 64 + c2 * 8];
      v0a = *(const short8*)&vn[(size_t)jr * 64 + c2 * 8];
      v1a = *(const short8*)&vn[(size_t)(jr + 16) * 64 + c2 * 8];
      v2a = *(const short8*)&vn[(size_t)(jr + 32) * 64 + c2 * 8];
      v3a = *(const short8*)&vn[(size_t)(jr + 48) * 64 + c2 * 8];
      const float* db = dist + ((size_t)b * N_ + (i0 + dr_r)) * N_ + j0 + KT + dr_c;
      #pragma unroll
      for (int p = 0; p < 4; ++p) dda[p] = *(const f32x4*)&db[p * 4];
    }
    // S = Q K^T
    f32x4 sa[4] = {{0,0,0,0},{0,0,0,0},{0,0,0,0},{0,0,0,0}};
    #pragma unroll
    for (int dblk = 0; dblk < 2; ++dblk)
      #pragma unroll
      for (int fj = 0; fj < 4; ++fj) {
        int j2 = fj * 16 + l;
        short8 kf = *(const short8*)&Ks[j2 * 64 + (dblk << 5) + ((g ^ ((j2 >> 1) & 3)) << 3)];
        sa[fj] = __builtin_amdgcn_mfma_f32_16x16x32_bf16(qf[dblk], kf, sa[fj], 0, 0, 0);
      }
    // softmax (bias from LDS tile)
    float al_[4];
    int qloc = w * 16 + 4 * g;
    #pragma unroll
    for (int reg = 0; reg < 4; ++reg) {
      float svr[4];
      #pragma unroll
      for (int fj = 0; fj < 4; ++fj)
        svr[fj] = fmaf(sa[fj][reg], 0.125f,
                       bf2f(Bsb[(qloc + reg) * 68 + fj * 16 + l]));
      float rm = fmaxf(fmaxf(svr[0], svr[1]), fmaxf(svr[2], svr[3]));
      rm = fmaxf(rm, __shfl_xor(rm, 1, 64));
      rm = fmaxf(rm, __shfl_xor(rm, 2, 64));
      rm = fmaxf(rm, __shfl_xor(rm, 4, 64));
      rm = fmaxf(rm, __shfl_xor(rm, 8, 64));
      float mn = fmaxf(m_[reg], rm);
      float al = __expf(m_[reg] - mn);
      m_[reg] = mn;
      al_[reg] = al;
      float ps = 0.f;
      int qlq = 4 * g + reg;
      int rowoff = qlq * 64;
      int swz = (qlq >> 1) & 3;
      #pragma unroll
      for (int fj = 0; fj < 4; ++fj) {
        float p = __expf(svr[fj] - mn);
        ps += p;
        int kgx = ((fj & 1) << 1) | (l >> 3);
        Ps[w][rowoff + ((fj >> 1) << 5) + ((kgx ^ swz) << 3) + (l & 7)] = f2bf(p);
      }
      ps += __shfl_xor(ps, 1, 64);
      ps += __shfl_xor(ps, 2, 64);
      ps += __shfl_xor(ps, 4, 64);
      ps += __shfl_xor(ps, 8, 64);
      l_[reg] = l_[reg] * al + ps;
    }
    #pragma unroll
    for (int fd = 0; fd < 4; ++fd)
      #pragma unroll
      for (int reg = 0; reg < 4; ++reg) acc[fd][reg] *= al_[reg];
    // O += P V
    #pragma unroll
    for (int jj = 0; jj < 2; ++jj) {
      short8 pa = *(const short8*)&Ps[w][l * 64 + (jj << 5) + ((g ^ ((l >> 1) & 3)) << 3)];
      #pragma unroll
      for (int fd = 0; fd < 4; ++fd) {
        int d2 = fd * 16 + l;
        short8 vf = *(const short8*)&Vt[d2 * 64 + (jj << 5) + ((g ^ ((d2 >> 1) & 3)) << 3)];
        acc[fd] = __builtin_amdgcn_mfma_f32_16x16x32_bf16(pa, vf, acc[fd], 0, 0, 0);
      }
    }
    __syncthreads();
    if (tt + 1 < NTH) {
      stK(k0a, jr); stK(k1a, jr + 16); stK(k2a, jr + 32); stK(k3a, jr + 48);
      stV(v0a, jr); stV(v1a, jr + 16); stV(v2a, jr + 32); stV(v3a, jr + 48);
      const int jn = j0 + KT;
      #pragma unroll
      for (int p = 0; p < 4; ++p) {
        ushort4 ov;
        #pragma unroll
        for (int e = 0; e < 4; ++e) {
          int jcol = dr_c + p * 4 + e;
          float u = dda[p][e] * ((float)TAB_ / MAXD);
          int it = (int)u;
          it = it < 0 ? 0 : (it > TAB_ - 1 ? TAB_ - 1 : it);
          float f = u - (float)it;
          float2 tv = tl2[it];
          ((ushort*)&ov)[e] = f2bf(tv.x + f * (tv.y - tv.x) + mfl[jn + jcol]);
        }
        *(ushort4*)&Bsb[dr_r * 68 + dr_c + p * 4] = ov;
      }
    }
    __syncthreads();
  }
  // epilogue: unnormalized partials + (m,l)
  const size_t pbase = (((size_t)(b * NJH + jh) * NH_ + h) * N_) + i0;
  #pragma unroll
  for (int reg = 0; reg < 4; ++reg) {
    int rowl = w * 16 + 4 * g + reg;
    float* op = Op + (pbase + rowl) * HD_ + l;
    #pragma unroll
    for (int fd = 0; fd < 4; ++fd) op[fd * 16] = acc[fd][reg];
    if (l == 0) ml[pbase + rowl] = make_float2(m_[reg], l_[reg]);
  }
}

// ---------------- combine j-split partials ----------------
__global__ __launch_bounds__(256) void comb_k(const float* __restrict__ Op,
                                              const float2* __restrict__ ml,
                                              ushort* __restrict__ ao) {
  int idx = blockIdx.x * 256 + threadIdx.x;
  int row = idx >> 4;
  int dq = (idx & 15) * 4;
  int b = row >> 13, h = (row >> 10) & 7, n = row & 1023;
  size_t p0 = (((size_t)(b * NJH + 0) * NH_ + h) * N_) + n;
  size_t p1 = (((size_t)(b * NJH + 1) * NH_ + h) * N_) + n;
  float2 v0 = ml[p0], v1 = ml[p1];
  float M = fmaxf(v0.x, v1.x);
  float a0 = __expf(v0.x - M), a1 = __expf(v1.x - M);
  float inv = 1.0f / (v0.y * a0 + v1.y * a1);
  float4 O0 = *(const float4*)&Op[p0 * HD_ + dq];
  float4 O1 = *(const float4*)&Op[p1 * HD_ + dq];
  ushort4 o;
  o.x = f2bf((O0.x * a0 + O1.x * a1) * inv);
  o.y = f2bf((O0.y * a0 + O1.y * a1) * inv);
  o.z = f2bf((O0.z * a0 + O1.z * a1) * inv);
  o.w = f2bf((O0.w * a0 + O1.w * a1) * inv);
  *(ushort4*)&ao[((size_t)(b * N_ + n)) * H_ + h * HD_ + dq] = o;
}

extern "C" void kernel_launch(void* const* d_in, const int* in_sizes, int n_in,
                              void* d_out, int out_size, void* d_ws, size_t ws_size,
                              hipStream_t stream) {
  const float* x = (const float*)d_in[0];
  const float* distances = (const float*)d_in[1];
  const int* mask = (const int*)d_in[2];
  const float* widths = (const float*)d_in[3];
  const float* dp_w = (const float*)d_in[4];
  const float* dp_b = (const float*)d_in[5];
  const float* wq = (const float*)d_in[6];
  const float* bq = (const float*)d_in[7];
  const float* wk = (const float*)d_in[8];
  const float* bk = (const float*)d_in[9];
  const float* wv = (const float*)d_in[10];
  const float* bv = (const float*)d_in[11];
  const float* wo = (const float*)d_in[12];
  const float* bo = (const float*)d_in[13];
  const float* ln1_g = (const float*)d_in[14];
  const float* ln1_b = (const float*)d_in[15];
  const float* ln2_g = (const float*)d_in[16];
  const float* ln2_b = (const float*)d_in[17];
  const float* w1 = (const float*)d_in[18];
  const float* b1 = (const float*)d_in[19];
  const float* w2 = (const float*)d_in[20];
  const float* b2 = (const float*)d_in[21];
  float* out = (float*)d_out;
  float* wsf = (float*)d_ws;

  const size_t M1 = (size_t)1 << 20;
  ushort* qkvb = (ushort*)wsf;                       // 3M bf16
  float* x1 = wsf + 2 * M1;                          // 1M f32
  ushort* hbuf = (ushort*)(wsf + 3 * M1);            // 4M bf16
  ushort* xn = (ushort*)(wsf + 5 * M1);              // 1M bf16
  ushort* xn2 = (ushort*)(wsf + 5 * M1 + M1 / 2);
  ushort* ao = (ushort*)(wsf + 6 * M1);              // 1M bf16
  ushort* wT4 = (ushort*)(wsf + 6 * M1 + M1 / 2);    // 4x 512x512 bf16
  ushort* w1T = (ushort*)(wsf + 7 * M1);             // [2048][512] bf16
  ushort* w2T = (ushort*)(wsf + 7 * M1 + M1 / 2);    // [512][2048] bf16
  float* tabf = wsf + 8 * M1;                        // 8200 f32
  float2* tab2 = (float2*)(wsf + 8 * M1 + 16384);    // 8200 float2
  float* Op = wsf + 9 * M1;                          // 2M f32 partials
  float2* ml = (float2*)(wsf + 11 * M1);             // 32K float2

  transp_k<<<dim3(16, 16, 4), 256, 0, stream>>>(wq, wk, wv, wo, wT4, 512, 512);
  transp_k<<<dim3(64, 16, 1), 256, 0, stream>>>(w1, w1, w1, w1, w1T, 512, 2048);
  transp_k<<<dim3(16, 64, 1), 256, 0, stream>>>(w2, w2, w2, w2, w2T, 2048, 512);
  tab_k<<<5, 256, 0, stream>>>(widths, dp_w, dp_b, tabf);
  tab2_k<<<33, 256, 0, stream>>>(tabf, tab2);

  ln_k<<<B_ * N_, 128, 0, stream>>>(x, ln1_g, ln1_b, xn);

  mfma_gemm<64, 64, EPI_QKV><<<dim3(8, 32, 3), 256, 0, stream>>>(
      xn, wT4, bq, bk, bv, nullptr, qkvb, 512, 512);

  attn_k<<<dim3(N_ / QT, NH_, B_ * NJH), 128, 0, stream>>>(
      qkvb, qkvb + M1, qkvb + 2 * M1, distances, mask, tab2, Op, ml);
  comb_k<<<1024, 256, 0, stream>>>(Op, ml, ao);

  mfma_gemm<64, 64, EPI_RES><<<dim3(8, 32, 1), 256, 0, stream>>>(
      ao, wT4 + (size_t)3 * 512 * 512, bo, bo, bo, x, x1, 512, 512);

  ln_k<<<B_ * N_, 128, 0, stream>>>(x1, ln2_g, ln2_b, xn2);

  mfma_gemm<128, 128, EPI_GELU><<<dim3(16, 16, 1), 256, 0, stream>>>(
      xn2, w1T, b1, b1, b1, nullptr, hbuf, 512, 2048);

  mfma_gemm<64, 64, EPI_RES><<<dim3(8, 32, 1), 256, 0, stream>>>(
      hbuf, w2T, b2, b2, b2, x1, out, 2048, 512);
}

// Round 6
// 123.949 us; speedup vs baseline: 5.5239x; 1.1070x over previous
//
#include <hip/hip_runtime.h>
#include <hip/hip_bf16.h>
#include <math.h>

#define B_ 2
#define N_ 1024
#define H_ 512
#define NH_ 8
#define HD_ 64
#define G_ 50
#define TAB_ 1024
constexpr float MAXD = 10.0f;

typedef __attribute__((ext_vector_type(8))) short short8;
typedef __attribute__((ext_vector_type(4))) float f32x4;

__device__ inline ushort f2bf(float v) {
  __hip_bfloat16 h = __float2bfloat16(v);
  return *(ushort*)&h;
}
__device__ inline float bf2f(ushort u) {
  unsigned x = ((unsigned)u) << 16;
  return __uint_as_float(x);
}

// ---------------- LayerNorm (f32 in -> bf16 out) ----------------
__global__ __launch_bounds__(128) void ln_k(const float* __restrict__ x,
                                            const float* __restrict__ g,
                                            const float* __restrict__ b,
                                            ushort* __restrict__ out) {
  int row = blockIdx.x;
  const float* xr = x + (size_t)row * H_;
  int t = threadIdx.x;
  float4 v = *(const float4*)(xr + t * 4);
  float s = v.x + v.y + v.z + v.w;
  float sq = v.x * v.x + v.y * v.y + v.z * v.z + v.w * v.w;
  #pragma unroll
  for (int m = 1; m < 64; m <<= 1) {
    s += __shfl_xor(s, m, 64);
    sq += __shfl_xor(sq, m, 64);
  }
  __shared__ float red[2][2];
  int wid = t >> 6;
  if ((t & 63) == 0) { red[wid][0] = s; red[wid][1] = sq; }
  __syncthreads();
  s = red[0][0] + red[1][0];
  sq = red[0][1] + red[1][1];
  float mu = s * (1.0f / H_);
  float var = sq * (1.0f / H_) - mu * mu;
  float rs = rsqrtf(var + 1e-5f);
  float4 gg = *(const float4*)(g + t * 4);
  float4 bb = *(const float4*)(b + t * 4);
  ushort4 o;
  o.x = f2bf((v.x - mu) * rs * gg.x + bb.x);
  o.y = f2bf((v.y - mu) * rs * gg.y + bb.y);
  o.z = f2bf((v.z - mu) * rs * gg.z + bb.z);
  o.w = f2bf((v.w - mu) * rs * gg.w + bb.w);
  *(ushort4*)(out + (size_t)row * H_ + t * 4) = o;
}

// ---------------- Bias table: tabf[t][h] ----------------
__global__ void tab_k(const float* __restrict__ widths, const float* __restrict__ dp_w,
                      const float* __restrict__ dp_b, float* __restrict__ tab) {
  int t = blockIdx.x * 256 + threadIdx.x;
  if (t > TAB_) return;
  float d = (float)t * (MAXD / TAB_);
  float acc[NH_];
  #pragma unroll
  for (int h = 0; h < NH_; ++h) acc[h] = dp_b[h];
  for (int g = 0; g < G_; ++g) {
    float c = (float)g * (MAXD / 49.0f);
    float w = widths[g];
    float diff = d - c;
    float e = expf(-diff * diff / (2.0f * w * w));
    #pragma unroll
    for (int h = 0; h < NH_; ++h) acc[h] += e * dp_w[g * NH_ + h];
  }
  #pragma unroll
  for (int h = 0; h < NH_; ++h) tab[t * NH_ + h] = acc[h];
}

// tab2[h][t] = (tabf[t][h], tabf[t+1][h])
__global__ void tab2_k(const float* __restrict__ tabf, float2* __restrict__ tab2) {
  int i = blockIdx.x * 256 + threadIdx.x;
  if (i >= NH_ * (TAB_ + 1)) return;
  int h = i / (TAB_ + 1), t = i % (TAB_ + 1);
  int t1 = t < TAB_ ? t + 1 : t;
  tab2[i] = make_float2(tabf[t * NH_ + h], tabf[t1 * NH_ + h]);
}

// ---------------- Transpose+convert: src f32 [R][C] -> dst bf16 [C][R] ----------------
__global__ __launch_bounds__(256) void transp_k(const float* s0, const float* s1,
                                                const float* s2, const float* s3,
                                                ushort* __restrict__ dst, int R, int C) {
  const float* src = (blockIdx.z == 0) ? s0 : (blockIdx.z == 1) ? s1
                   : (blockIdx.z == 2) ? s2 : s3;
  ushort* d = dst + (size_t)blockIdx.z * R * C;
  __shared__ float tile[32][33];
  int t = threadIdx.x;
  int r0 = blockIdx.y * 32, c0 = blockIdx.x * 32;
  int rr = t >> 5, cc = t & 31;
  #pragma unroll
  for (int p = 0; p < 4; ++p)
    tile[rr + p * 8][cc] = src[(size_t)(r0 + rr + p * 8) * C + c0 + cc];
  __syncthreads();
  #pragma unroll
  for (int p = 0; p < 4; ++p)
    d[(size_t)(c0 + rr + p * 8) * R + r0 + cc] = f2bf(tile[cc][rr + p * 8]);
}

// ---------------- bf16 MFMA GEMM, reg double-buffer, conflict-free swizzle ----------
enum { EPI_QKV = 1, EPI_RES = 2, EPI_GELU = 3 };

template <int BM, int BN, int EPI>
__global__ __launch_bounds__(256) void mfma_gemm(const ushort* __restrict__ A,
                                                 const ushort* __restrict__ Bt,
                                                 const float* __restrict__ b0,
                                                 const float* __restrict__ b1,
                                                 const float* __restrict__ b2,
                                                 const float* __restrict__ resid,
                                                 void* __restrict__ outv,
                                                 int K, int Nc) {
  __shared__ ushort As[BM * 32];
  __shared__ ushort Bs[BN * 32];
  int t = threadIdx.x;
  int z = blockIdx.z;
  const ushort* Bz = Bt + (size_t)z * Nc * K;
  const float* bias = (z == 0) ? b0 : (z == 1) ? b1 : b2;
  int m0 = blockIdx.y * BM, n0 = blockIdx.x * BN;
  int lane = t & 63, w = t >> 6, wr = w >> 1, wc = w & 1;
  int lrow = lane & 15, lkg = lane >> 4;
  constexpr int NFM = BM / 32, NFN = BN / 32;
  constexpr int AL = BM / 64, BL = BN / 64;
  f32x4 acc[NFM][NFN] = {};
  int kg = t & 3, r0 = t >> 2;

  short8 raA[AL], rbA[BL], raB[AL], rbB[BL];
  auto loadT = [&](int kt, short8 (&la)[AL], short8 (&lb)[BL]) {
    #pragma unroll
    for (int p = 0; p < AL; ++p)
      la[p] = *(const short8*)&A[(size_t)(m0 + r0 + p * 64) * K + kt + kg * 8];
    #pragma unroll
    for (int p = 0; p < BL; ++p)
      lb[p] = *(const short8*)&Bz[(size_t)(n0 + r0 + p * 64) * K + kt + kg * 8];
  };
  auto storeT = [&](short8 (&la)[AL], short8 (&lb)[BL]) {
    #pragma unroll
    for (int p = 0; p < AL; ++p) {
      int r = r0 + p * 64;
      *(short8*)&As[r * 32 + ((kg ^ (r & 3)) << 3)] = la[p];
    }
    #pragma unroll
    for (int p = 0; p < BL; ++p) {
      int r = r0 + p * 64;
      *(short8*)&Bs[r * 32 + ((kg ^ (r & 3)) << 3)] = lb[p];
    }
  };
  auto compute = [&]() {
    short8 af[NFM], bfr[NFN];
    #pragma unroll
    for (int fm = 0; fm < NFM; ++fm) {
      int r = wr * (BM / 2) + fm * 16 + lrow;
      af[fm] = *(const short8*)&As[r * 32 + ((lkg ^ (r & 3)) << 3)];
    }
    #pragma unroll
    for (int fn = 0; fn < NFN; ++fn) {
      int r = wc * (BN / 2) + fn * 16 + lrow;
      bfr[fn] = *(const short8*)&Bs[r * 32 + ((lkg ^ (r & 3)) << 3)];
    }
    #pragma unroll
    for (int fm = 0; fm < NFM; ++fm)
      #pragma unroll
      for (int fn = 0; fn < NFN; ++fn)
        acc[fm][fn] = __builtin_amdgcn_mfma_f32_16x16x32_bf16(af[fm], bfr[fn],
                                                              acc[fm][fn], 0, 0, 0);
  };

  loadT(0, raA, rbA);
  for (int kt = 0; kt < K; kt += 64) {
    __syncthreads();
    storeT(raA, rbA);
    __syncthreads();
    loadT(kt + 32, raB, rbB);
    compute();
    __syncthreads();
    storeT(raB, rbB);
    __syncthreads();
    if (kt + 64 < K) loadT(kt + 64, raA, rbA);
    compute();
  }

  int rbase = (lane >> 4) * 4;
  #pragma unroll
  for (int fm = 0; fm < NFM; ++fm) {
    #pragma unroll
    for (int fn = 0; fn < NFN; ++fn) {
      #pragma unroll
      for (int j = 0; j < 4; ++j) {
        int row = m0 + wr * (BM / 2) + fm * 16 + rbase + j;
        int col = n0 + wc * (BN / 2) + fn * 16 + lrow;
        float v = acc[fm][fn][j] + bias[col];
        if constexpr (EPI == EPI_QKV) {
          ushort* q = (ushort*)outv + (size_t)z * (1 << 20);
          int bb = row >> 10, n = row & (N_ - 1);
          int h = col >> 6, d = col & 63;
          if (z < 2)
            q[(((size_t)(bb * NH_ + h)) * N_ + n) * HD_ + d] = f2bf(v);
          else  // V stored transposed: [b][h][d][n]
            q[(((size_t)(bb * NH_ + h)) * HD_ + d) * N_ + n] = f2bf(v);
        } else if constexpr (EPI == EPI_RES) {
          ((float*)outv)[(size_t)row * Nc + col] =
              resid[(size_t)row * Nc + col] + v;
        } else {  // GELU -> bf16
          ((ushort*)outv)[(size_t)row * Nc + col] =
              f2bf(0.5f * v * (1.0f + erff(v * 0.70710678118654752f)));
        }
      }
    }
  }
}

// ---------------- MFMA flash attention, j-split, conflict-free LDS ----------------
constexpr int QT = 64, KT = 64, NJH = 2, NTH = N_ / (KT * NJH);  // 8 tiles/block
constexpr int JH = N_ / NJH;  // 512

__global__ __launch_bounds__(256) void attn_k(
    const ushort* __restrict__ q, const ushort* __restrict__ k,
    const ushort* __restrict__ v, const float* __restrict__ dist,
    const int* __restrict__ mask, const float2* __restrict__ tab2g,
    float* __restrict__ Op, float2* __restrict__ ml) {
  int qt = blockIdx.x, h = blockIdx.y, z = blockIdx.z;
  int b = z >> 1, jh = z & 1;
  int i0 = qt * QT;
  int jbase = jh * JH;
  __shared__ ushort Ks[KT * 64];     // [j][d], chunk ^= (j&7)
  __shared__ ushort Vt[64 * KT];     // [d][j], chunk ^= (d&7)
  __shared__ ushort Bsb[QT * 68];    // bias tile [q][j], stride 68
  __shared__ ushort Ps[4][16 * 64];  // per-warp P [q][j], chunk ^= (q&7)
  __shared__ float2 tl2[TAB_ + 1];
  __shared__ float mfl[JH];
  int t = threadIdx.x;
  int lane = t & 63, w = t >> 6;
  int l = lane & 15, g = lane >> 4;

  for (int i = t; i <= TAB_; i += 256) tl2[i] = tab2g[h * (TAB_ + 1) + i];
  for (int i = t; i < JH; i += 256) mfl[i] = (mask[b * N_ + jbase + i] == 0) ? -1e9f : 0.0f;

  const size_t ho = ((size_t)(b * NH_ + h)) * N_ * HD_;
  const ushort* qb = q + ho;
  const ushort* kb = k + ho;
  const ushort* vb = v + ho;  // V^T layout: [d][N_]

  int qrow = i0 + w * 16 + l;
  short8 qf[2];
  qf[0] = *(const short8*)&qb[(size_t)qrow * 64 + g * 8];
  qf[1] = *(const short8*)&qb[(size_t)qrow * 64 + 32 + g * 8];

  int c2 = t & 7, jr = t >> 3;             // staging: chunk 0..7, row 0..31 (+32)
  int dr_r = t >> 2, dr_c = (t & 3) * 16;  // dist staging: row 0..63, col-base

  auto stK = [&](short8 val, int j2) {
    *(short8*)&Ks[j2 * 64 + ((c2 ^ (j2 & 7)) << 3)] = val;
  };
  auto stV = [&](short8 val, int d) {
    *(short8*)&Vt[d * 64 + ((c2 ^ (d & 7)) << 3)] = val;
  };

  // --- prologue: load + stage tile 0 ---
  short8 k0a, k1a, v0a, v1a;
  f32x4 dda[4];
  {
    const ushort* kn = kb + (size_t)jbase * 64;
    const ushort* vn = vb + jbase;
    k0a = *(const short8*)&kn[(size_t)jr * 64 + c2 * 8];
    k1a = *(const short8*)&kn[(size_t)(jr + 32) * 64 + c2 * 8];
    v0a = *(const short8*)&vn[(size_t)jr * N_ + c2 * 8];
    v1a = *(const short8*)&vn[(size_t)(jr + 32) * N_ + c2 * 8];
    const float* db = dist + ((size_t)b * N_ + (i0 + dr_r)) * N_ + jbase + dr_c;
    #pragma unroll
    for (int p = 0; p < 4; ++p) dda[p] = *(const f32x4*)&db[p * 4];
  }
  __syncthreads();  // tl2 + mfl ready
  {
    stK(k0a, jr); stK(k1a, jr + 32);
    stV(v0a, jr); stV(v1a, jr + 32);
    #pragma unroll
    for (int p = 0; p < 4; ++p) {
      ushort4 ov;
      #pragma unroll
      for (int e = 0; e < 4; ++e) {
        int jcol = dr_c + p * 4 + e;
        float u = dda[p][e] * ((float)TAB_ / MAXD);
        int it = (int)u;
        it = it < 0 ? 0 : (it > TAB_ - 1 ? TAB_ - 1 : it);
        float f = u - (float)it;
        float2 tv = tl2[it];
        ((ushort*)&ov)[e] = f2bf(tv.x + f * (tv.y - tv.x) + mfl[jcol]);
      }
      *(ushort4*)&Bsb[dr_r * 68 + dr_c + p * 4] = ov;
    }
  }
  __syncthreads();

  float m_[4] = {-1e30f, -1e30f, -1e30f, -1e30f};
  float l_[4] = {0.f, 0.f, 0.f, 0.f};
  f32x4 acc[4] = {{0,0,0,0},{0,0,0,0},{0,0,0,0},{0,0,0,0}};

  for (int tt = 0; tt < NTH; ++tt) {
    const int j0 = jbase + tt * KT;
    if (tt + 1 < NTH) {
      const ushort* kn = kb + (size_t)(j0 + KT) * 64;
      const ushort* vn = vb + (j0 + KT);
      k0a = *(const short8*)&kn[(size_t)jr * 64 + c2 * 8];
      k1a = *(const short8*)&kn[(size_t)(jr + 32) * 64 + c2 * 8];
      v0a = *(const short8*)&vn[(size_t)jr * N_ + c2 * 8];
      v1a = *(const short8*)&vn[(size_t)(jr + 32) * N_ + c2 * 8];
      const float* db = dist + ((size_t)b * N_ + (i0 + dr_r)) * N_ + j0 + KT + dr_c;
      #pragma unroll
      for (int p = 0; p < 4; ++p) dda[p] = *(const f32x4*)&db[p * 4];
    }
    // S = Q K^T
    f32x4 sa[4] = {{0,0,0,0},{0,0,0,0},{0,0,0,0},{0,0,0,0}};
    #pragma unroll
    for (int dblk = 0; dblk < 2; ++dblk)
      #pragma unroll
      for (int fj = 0; fj < 4; ++fj) {
        int j2 = fj * 16 + l;
        short8 kf = *(const short8*)&Ks[j2 * 64 + (((dblk * 4 + g) ^ (j2 & 7)) << 3)];
        sa[fj] = __builtin_amdgcn_mfma_f32_16x16x32_bf16(qf[dblk], kf, sa[fj], 0, 0, 0);
      }
    // softmax (bias from LDS tile)
    float al_[4];
    int qloc = w * 16 + 4 * g;
    #pragma unroll
    for (int reg = 0; reg < 4; ++reg) {
      float svr[4];
      #pragma unroll
      for (int fj = 0; fj < 4; ++fj)
        svr[fj] = fmaf(sa[fj][reg], 0.125f,
                       bf2f(Bsb[(qloc + reg) * 68 + fj * 16 + l]));
      float rm = fmaxf(fmaxf(svr[0], svr[1]), fmaxf(svr[2], svr[3]));
      rm = fmaxf(rm, __shfl_xor(rm, 1, 64));
      rm = fmaxf(rm, __shfl_xor(rm, 2, 64));
      rm = fmaxf(rm, __shfl_xor(rm, 4, 64));
      rm = fmaxf(rm, __shfl_xor(rm, 8, 64));
      float mn = fmaxf(m_[reg], rm);
      float al = __expf(m_[reg] - mn);
      m_[reg] = mn;
      al_[reg] = al;
      float ps = 0.f;
      int qlq = 4 * g + reg;
      #pragma unroll
      for (int fj = 0; fj < 4; ++fj) {
        float p = __expf(svr[fj] - mn);
        ps += p;
        int c = fj * 2 + (l >> 3);
        Ps[w][qlq * 64 + ((c ^ (qlq & 7)) << 3) + (l & 7)] = f2bf(p);
      }
      ps += __shfl_xor(ps, 1, 64);
      ps += __shfl_xor(ps, 2, 64);
      ps += __shfl_xor(ps, 4, 64);
      ps += __shfl_xor(ps, 8, 64);
      l_[reg] = l_[reg] * al + ps;
    }
    #pragma unroll
    for (int fd = 0; fd < 4; ++fd)
      #pragma unroll
      for (int reg = 0; reg < 4; ++reg) acc[fd][reg] *= al_[reg];
    // O += P V   (P A-frags, V^T B-frags)
    #pragma unroll
    for (int jj = 0; jj < 2; ++jj) {
      short8 pa = *(const short8*)&Ps[w][l * 64 + (((jj * 4 + g) ^ (l & 7)) << 3)];
      #pragma unroll
      for (int fd = 0; fd < 4; ++fd) {
        int d2 = fd * 16 + l;
        short8 vf = *(const short8*)&Vt[d2 * 64 + (((jj * 4 + g) ^ (d2 & 7)) << 3)];
        acc[fd] = __builtin_amdgcn_mfma_f32_16x16x32_bf16(pa, vf, acc[fd], 0, 0, 0);
      }
    }
    __syncthreads();
    if (tt + 1 < NTH) {
      stK(k0a, jr); stK(k1a, jr + 32);
      stV(v0a, jr); stV(v1a, jr + 32);
      const int jloc = (tt + 1) * KT;
      #pragma unroll
      for (int p = 0; p < 4; ++p) {
        ushort4 ov;
        #pragma unroll
        for (int e = 0; e < 4; ++e) {
          int jcol = dr_c + p * 4 + e;
          float u = dda[p][e] * ((float)TAB_ / MAXD);
          int it = (int)u;
          it = it < 0 ? 0 : (it > TAB_ - 1 ? TAB_ - 1 : it);
          float f = u - (float)it;
          float2 tv = tl2[it];
          ((ushort*)&ov)[e] = f2bf(tv.x + f * (tv.y - tv.x) + mfl[jloc + jcol]);
        }
        *(ushort4*)&Bsb[dr_r * 68 + dr_c + p * 4] = ov;
      }
    }
    __syncthreads();
  }
  // epilogue: unnormalized partials + (m,l)
  const size_t pbase = (((size_t)(b * NJH + jh) * NH_ + h) * N_) + i0;
  #pragma unroll
  for (int reg = 0; reg < 4; ++reg) {
    int rowl = w * 16 + 4 * g + reg;
    float* op = Op + (pbase + rowl) * HD_ + l;
    #pragma unroll
    for (int fd = 0; fd < 4; ++fd) op[fd * 16] = acc[fd][reg];
    if (l == 0) ml[pbase + rowl] = make_float2(m_[reg], l_[reg]);
  }
}

// ---------------- combine j-split partials ----------------
__global__ __launch_bounds__(256) void comb_k(const float* __restrict__ Op,
                                              const float2* __restrict__ ml,
                                              ushort* __restrict__ ao) {
  int idx = blockIdx.x * 256 + threadIdx.x;
  int row = idx >> 4;
  int dq = (idx & 15) * 4;
  int b = row >> 13, h = (row >> 10) & 7, n = row & 1023;
  size_t p0 = (((size_t)(b * NJH + 0) * NH_ + h) * N_) + n;
  size_t p1 = (((size_t)(b * NJH + 1) * NH_ + h) * N_) + n;
  float2 v0 = ml[p0], v1 = ml[p1];
  float M = fmaxf(v0.x, v1.x);
  float a0 = __expf(v0.x - M), a1 = __expf(v1.x - M);
  float inv = 1.0f / (v0.y * a0 + v1.y * a1);
  float4 O0 = *(const float4*)&Op[p0 * HD_ + dq];
  float4 O1 = *(const float4*)&Op[p1 * HD_ + dq];
  ushort4 o;
  o.x = f2bf((O0.x * a0 + O1.x * a1) * inv);
  o.y = f2bf((O0.y * a0 + O1.y * a1) * inv);
  o.z = f2bf((O0.z * a0 + O1.z * a1) * inv);
  o.w = f2bf((O0.w * a0 + O1.w * a1) * inv);
  *(ushort4*)&ao[((size_t)(b * N_ + n)) * H_ + h * HD_ + dq] = o;
}

extern "C" void kernel_launch(void* const* d_in, const int* in_sizes, int n_in,
                              void* d_out, int out_size, void* d_ws, size_t ws_size,
                              hipStream_t stream) {
  const float* x = (const float*)d_in[0];
  const float* distances = (const float*)d_in[1];
  const int* mask = (const int*)d_in[2];
  const float* widths = (const float*)d_in[3];
  const float* dp_w = (const float*)d_in[4];
  const float* dp_b = (const float*)d_in[5];
  const float* wq = (const float*)d_in[6];
  const float* bq = (const float*)d_in[7];
  const float* wk = (const float*)d_in[8];
  const float* bk = (const float*)d_in[9];
  const float* wv = (const float*)d_in[10];
  const float* bv = (const float*)d_in[11];
  const float* wo = (const float*)d_in[12];
  const float* bo = (const float*)d_in[13];
  const float* ln1_g = (const float*)d_in[14];
  const float* ln1_b = (const float*)d_in[15];
  const float* ln2_g = (const float*)d_in[16];
  const float* ln2_b = (const float*)d_in[17];
  const float* w1 = (const float*)d_in[18];
  const float* b1 = (const float*)d_in[19];
  const float* w2 = (const float*)d_in[20];
  const float* b2 = (const float*)d_in[21];
  float* out = (float*)d_out;
  float* wsf = (float*)d_ws;

  const size_t M1 = (size_t)1 << 20;
  ushort* qkvb = (ushort*)wsf;                       // 3M bf16 (V transposed)
  float* x1 = wsf + 2 * M1;                          // 1M f32
  ushort* hbuf = (ushort*)(wsf + 3 * M1);            // 4M bf16
  ushort* xn = (ushort*)(wsf + 5 * M1);              // 1M bf16
  ushort* xn2 = (ushort*)(wsf + 5 * M1 + M1 / 2);
  ushort* ao = (ushort*)(wsf + 6 * M1);              // 1M bf16
  ushort* wT4 = (ushort*)(wsf + 6 * M1 + M1 / 2);    // 4x 512x512 bf16
  ushort* w1T = (ushort*)(wsf + 7 * M1);             // [2048][512] bf16
  ushort* w2T = (ushort*)(wsf + 7 * M1 + M1 / 2);    // [512][2048] bf16
  float* tabf = wsf + 8 * M1;                        // 8200 f32
  float2* tab2 = (float2*)(wsf + 8 * M1 + 16384);    // 8200 float2
  float* Op = wsf + 9 * M1;                          // 2M f32 partials
  float2* ml = (float2*)(wsf + 11 * M1);             // 32K float2

  transp_k<<<dim3(16, 16, 4), 256, 0, stream>>>(wq, wk, wv, wo, wT4, 512, 512);
  transp_k<<<dim3(64, 16, 1), 256, 0, stream>>>(w1, w1, w1, w1, w1T, 512, 2048);
  transp_k<<<dim3(16, 64, 1), 256, 0, stream>>>(w2, w2, w2, w2, w2T, 2048, 512);
  tab_k<<<5, 256, 0, stream>>>(widths, dp_w, dp_b, tabf);
  tab2_k<<<33, 256, 0, stream>>>(tabf, tab2);

  ln_k<<<B_ * N_, 128, 0, stream>>>(x, ln1_g, ln1_b, xn);

  mfma_gemm<64, 64, EPI_QKV><<<dim3(8, 32, 3), 256, 0, stream>>>(
      xn, wT4, bq, bk, bv, nullptr, qkvb, 512, 512);

  attn_k<<<dim3(N_ / QT, NH_, B_ * NJH), 256, 0, stream>>>(
      qkvb, qkvb + M1, qkvb + 2 * M1, distances, mask, tab2, Op, ml);
  comb_k<<<1024, 256, 0, stream>>>(Op, ml, ao);

  mfma_gemm<64, 64, EPI_RES><<<dim3(8, 32, 1), 256, 0, stream>>>(
      ao, wT4 + (size_t)3 * 512 * 512, bo, bo, bo, x, x1, 512, 512);

  ln_k<<<B_ * N_, 128, 0, stream>>>(x1, ln2_g, ln2_b, xn2);

  mfma_gemm<128, 128, EPI_GELU><<<dim3(16, 16, 1), 256, 0, stream>>>(
      xn2, w1T, b1, b1, b1, nullptr, hbuf, 512, 2048);

  mfma_gemm<64, 64, EPI_RES><<<dim3(8, 32, 1), 256, 0, stream>>>(
      hbuf, w2T, b2, b2, b2, x1, out, 2048, 512);
}